// Round 1
// baseline (1875.744 us; speedup 1.0000x reference)
//
#include <hip/hip_runtime.h>
#include <math.h>

#define T 128
#define F 64
#define H1 32
#define G1 128   // 4*H1
#define H2 16
#define G2 64    // 4*H2

__device__ __forceinline__ float sigmoidf_(float x) {
    return 1.0f / (1.0f + __expf(-x));
}
__device__ __forceinline__ float tanhf_(float x) {
    // tanh(x) = 1 - 2/(exp(2x)+1); saturates correctly for |x| large
    return 1.0f - 2.0f / (__expf(2.0f * x) + 1.0f);
}

__global__ __launch_bounds__(256, 2) void lstm_fused_kernel(
    const float* __restrict__ x,     // [B,T,F]
    const float* __restrict__ W1f, const float* __restrict__ U1f, const float* __restrict__ b1f,
    const float* __restrict__ W1b, const float* __restrict__ U1b, const float* __restrict__ b1b,
    const float* __restrict__ W2f, const float* __restrict__ U2f, const float* __restrict__ b2f,
    const float* __restrict__ W2b, const float* __restrict__ U2b, const float* __restrict__ b2b,
    const float* __restrict__ W3, const float* __restrict__ b3,
    const float* __restrict__ W4, const float* __restrict__ b4,
    float* __restrict__ out)         // [B,2]
{
    __shared__ float x_s[T * F];         // 32 KB: this sample's input
    __shared__ float h1_s[T * (2*H1)];   // 32 KB: layer-1 concat output
    __shared__ float z_s[2][G1];         // gate pre-activations, layer 1
    __shared__ float hc_s[2][H1];        // current h, layer 1
    __shared__ float z2_s[2][G2];        // gate pre-activations, layer 2
    __shared__ float h2c_s[2][H2];       // current h, layer 2
    __shared__ float y1_s[8];            // dense hidden

    const int tid = threadIdx.x;
    const int b = blockIdx.x;
    const float* xb = x + (size_t)b * (T * F);

    // ---- stage x[b] into LDS (coalesced float4) ----
    {
        const float4* src = (const float4*)xb;
        float4* dst = (float4*)x_s;
        #pragma unroll
        for (int i = 0; i < (T*F/4)/256; ++i)
            dst[i*256 + tid] = src[i*256 + tid];
    }

    // ---- layer 1 setup: thread = (direction, gate column) ----
    const int dir = tid >> 7;       // 0 = forward, 1 = backward
    const int j   = tid & 127;      // gate column in [0,128)

    const float* W1 = dir ? W1b : W1f;
    const float* U1 = dir ? U1b : U1f;
    const float* B1 = dir ? b1b : b1f;

    float Wc[F];    // column j of W1 (coalesced loads across threads)
    float Uc[H1];   // column j of U1
    #pragma unroll
    for (int k = 0; k < F; ++k)  Wc[k] = W1[k*G1 + j];
    #pragma unroll
    for (int k = 0; k < H1; ++k) Uc[k] = U1[k*G1 + j];
    const float bj = B1[j];

    if (j < H1) hc_s[dir][j] = 0.0f;
    float c1 = 0.0f;                // cell state, owned by threads j<H1
    __syncthreads();

    // ---- layer 1 recurrence (both directions concurrently) ----
    for (int s = 0; s < T; ++s) {
        const int t = dir ? (T-1-s) : s;
        float z = bj;
        const float4* xt4 = (const float4*)(x_s + t*F);
        #pragma unroll
        for (int k4 = 0; k4 < F/4; ++k4) {
            float4 v = xt4[k4];   // LDS broadcast read
            z += v.x*Wc[4*k4+0] + v.y*Wc[4*k4+1] + v.z*Wc[4*k4+2] + v.w*Wc[4*k4+3];
        }
        const float4* h4 = (const float4*)(hc_s[dir]);
        #pragma unroll
        for (int k4 = 0; k4 < H1/4; ++k4) {
            float4 v = h4[k4];
            z += v.x*Uc[4*k4+0] + v.y*Uc[4*k4+1] + v.z*Uc[4*k4+2] + v.w*Uc[4*k4+3];
        }
        z_s[dir][j] = z;
        __syncthreads();
        if (j < H1) {
            const float zi = z_s[dir][j];
            const float zf = z_s[dir][H1   + j];
            const float zg = z_s[dir][2*H1 + j];
            const float zo = z_s[dir][3*H1 + j];
            const float ig = sigmoidf_(zi);
            const float fg = sigmoidf_(zf);
            const float gg = tanhf_(zg);
            const float og = sigmoidf_(zo);
            c1 = fg * c1 + ig * gg;
            const float h = og * tanhf_(c1);
            hc_s[dir][j] = h;
            h1_s[t*(2*H1) + dir*H1 + j] = h;   // concat: fwd cols [0,32), bwd [32,64)
        }
        __syncthreads();
    }

    // ---- layer 2 setup: threads 0..127 active; thread = (dir2, gate col) ----
    const int dir2 = (tid >> 6) & 1;
    const int j2   = tid & 63;
    float W2c[2*H1];
    float U2c[H2];
    float b2j = 0.0f;
    if (tid < 128) {
        const float* W2 = dir2 ? W2b : W2f;
        const float* U2 = dir2 ? U2b : U2f;
        const float* B2 = dir2 ? b2b : b2f;
        #pragma unroll
        for (int k = 0; k < 2*H1; ++k) W2c[k] = W2[k*G2 + j2];
        #pragma unroll
        for (int k = 0; k < H2; ++k)   U2c[k] = U2[k*G2 + j2];
        b2j = B2[j2];
        if (j2 < H2) h2c_s[dir2][j2] = 0.0f;
    }
    float c2 = 0.0f;
    __syncthreads();

    // ---- layer 2 recurrence ----
    for (int s = 0; s < T; ++s) {
        if (tid < 128) {
            const int t = dir2 ? (T-1-s) : s;
            float z = b2j;
            const float4* xt4 = (const float4*)(h1_s + t*(2*H1));
            #pragma unroll
            for (int k4 = 0; k4 < (2*H1)/4; ++k4) {
                float4 v = xt4[k4];
                z += v.x*W2c[4*k4+0] + v.y*W2c[4*k4+1] + v.z*W2c[4*k4+2] + v.w*W2c[4*k4+3];
            }
            const float4* h4 = (const float4*)(h2c_s[dir2]);
            #pragma unroll
            for (int k4 = 0; k4 < H2/4; ++k4) {
                float4 v = h4[k4];
                z += v.x*U2c[4*k4+0] + v.y*U2c[4*k4+1] + v.z*U2c[4*k4+2] + v.w*U2c[4*k4+3];
            }
            z2_s[dir2][j2] = z;
        }
        __syncthreads();
        if (tid < 128 && j2 < H2) {
            const float zi = z2_s[dir2][j2];
            const float zf = z2_s[dir2][H2   + j2];
            const float zg = z2_s[dir2][2*H2 + j2];
            const float zo = z2_s[dir2][3*H2 + j2];
            const float ig = sigmoidf_(zi);
            const float fg = sigmoidf_(zf);
            const float gg = tanhf_(zg);
            const float og = sigmoidf_(zo);
            c2 = fg * c2 + ig * gg;
            h2c_s[dir2][j2] = og * tanhf_(c2);
        }
        __syncthreads();
    }
    // h2f = h2c_s[0][:]  (state after processing t=127)
    // h2b = h2c_s[1][:]  (state after processing down to t=0)

    // ---- dense head: [h2f,h2b](32) @ W3(32x8) + b3 -> swish -> @ W4(8x2) + b4 -> sigmoid ----
    if (tid < 8) {
        float acc = b3[tid];
        #pragma unroll
        for (int k = 0; k < 2*H2; ++k) {
            const float v = (k < H2) ? h2c_s[0][k] : h2c_s[1][k - H2];
            acc += v * W3[k*8 + tid];
        }
        y1_s[tid] = acc * sigmoidf_(acc);  // swish
    }
    __syncthreads();
    if (tid < 2) {
        float acc = b4[tid];
        #pragma unroll
        for (int k = 0; k < 8; ++k) acc += y1_s[k] * W4[k*2 + tid];
        out[(size_t)b*2 + tid] = sigmoidf_(acc);
    }
}

extern "C" void kernel_launch(void* const* d_in, const int* in_sizes, int n_in,
                              void* d_out, int out_size, void* d_ws, size_t ws_size,
                              hipStream_t stream) {
    const float* x   = (const float*)d_in[0];
    const float* W1f = (const float*)d_in[1];
    const float* U1f = (const float*)d_in[2];
    const float* b1f = (const float*)d_in[3];
    const float* W1b = (const float*)d_in[4];
    const float* U1b = (const float*)d_in[5];
    const float* b1b = (const float*)d_in[6];
    const float* W2f = (const float*)d_in[7];
    const float* U2f = (const float*)d_in[8];
    const float* b2f = (const float*)d_in[9];
    const float* W2b = (const float*)d_in[10];
    const float* U2b = (const float*)d_in[11];
    const float* b2b = (const float*)d_in[12];
    const float* W3  = (const float*)d_in[13];
    const float* b3  = (const float*)d_in[14];
    const float* W4  = (const float*)d_in[15];
    const float* b4  = (const float*)d_in[16];

    const int B = in_sizes[0] / (T * F);
    lstm_fused_kernel<<<B, 256, 0, stream>>>(
        x, W1f, U1f, b1f, W1b, U1b, b1b,
        W2f, U2f, b2f, W2b, U2b, b2b,
        W3, b3, W4, b4, (float*)d_out);
}

// Round 2
// 1236.074 us; speedup vs baseline: 1.5175x; 1.5175x over previous
//
#include <hip/hip_runtime.h>
#include <hip/hip_bf16.h>
#include <math.h>

#define T 128
#define F 64
#define H1 32
#define G1 128   // 4*H1
#define H2 16
#define G2 64    // 4*H2
#define NG1 256  // both-dir gate width, layer 1
#define NG2 128  // both-dir gate width, layer 2
#define NH1 64   // concat h1 width

__device__ __forceinline__ float sigmoidf_(float x) {
    return 1.0f / (1.0f + __expf(-x));
}
__device__ __forceinline__ float tanhf_(float x) {
    return 1.0f - 2.0f / (__expf(2.0f * x) + 1.0f);
}
__device__ __forceinline__ float bfbits2f(unsigned short v) {
    union { unsigned u; float f; } c; c.u = ((unsigned)v) << 16; return c.f;
}

// ---------------- K1: xw1 = x @ [W1f|W1b] + bias -> bf16 [rows,256] ----------
__global__ __launch_bounds__(256, 4) void k1_xw1(
    const float* __restrict__ x,          // [rows, F] (chunk base)
    const float* __restrict__ W1f, const float* __restrict__ b1f,
    const float* __restrict__ W1b, const float* __restrict__ b1b,
    __hip_bfloat16* __restrict__ xw1)     // [rows, NG1]
{
    __shared__ float x_s[32 * F];         // 8 KB: 32 rows of x
    const int tid  = threadIdx.x;
    const int row0 = blockIdx.x * 32;
    {   // stage 32x64 floats = 512 float4
        const float4* src = (const float4*)(x + (size_t)row0 * F);
        float4* dst = (float4*)x_s;
        dst[tid]       = src[tid];
        dst[tid + 256] = src[tid + 256];
    }
    const int j = tid;                    // output gate column 0..255
    const float* Wcol;
    float bias;
    if (j < G1) { Wcol = W1f + j;        bias = b1f[j]; }
    else        { Wcol = W1b + (j - G1); bias = b1b[j - G1]; }

    float acc[32];
    #pragma unroll
    for (int r = 0; r < 32; ++r) acc[r] = bias;
    __syncthreads();

    for (int k4 = 0; k4 < F / 4; ++k4) {
        const float w0 = Wcol[(4 * k4 + 0) * G1];
        const float w1 = Wcol[(4 * k4 + 1) * G1];
        const float w2 = Wcol[(4 * k4 + 2) * G1];
        const float w3 = Wcol[(4 * k4 + 3) * G1];
        #pragma unroll
        for (int r = 0; r < 32; ++r) {
            const float4 xv = ((const float4*)(x_s + r * F))[k4];  // LDS broadcast
            acc[r] += xv.x * w0 + xv.y * w1 + xv.z * w2 + xv.w * w3;
        }
    }
    #pragma unroll
    for (int r = 0; r < 32; ++r)
        xw1[(size_t)(row0 + r) * NG1 + j] = __float2bfloat16(acc[r]);
}

// ---------------- K2: layer-1 bidirectional recurrence -----------------------
__global__ __launch_bounds__(256, 4) void k2_lstm1(
    const __hip_bfloat16* __restrict__ xw1,  // [chunkB*T, NG1]
    const float* __restrict__ U1f, const float* __restrict__ U1b,
    __hip_bfloat16* __restrict__ h1)         // [chunkB*T, NH1]
{
    __shared__ float hc_s[2][H1];
    __shared__ float z_s[2][G1];
    const int tid = threadIdx.x;
    const int dir = tid >> 7;            // 0 fwd, 1 bwd
    const int j   = tid & 127;           // gate column

    const __hip_bfloat16* xwp = xw1 + (size_t)blockIdx.x * T * NG1 + dir * G1 + j;
    __hip_bfloat16* h1p = h1 + (size_t)blockIdx.x * T * NH1;

    const float* U1 = dir ? U1b : U1f;
    float Uc[H1];
    #pragma unroll
    for (int k = 0; k < H1; ++k) Uc[k] = U1[k * G1 + j];

    if (j < H1) hc_s[dir][j] = 0.0f;
    float c = 0.0f;

    // software-prefetch of xw
    int t0 = dir ? (T - 1) : 0;
    float xw_cur = __bfloat162float(xwp[(size_t)t0 * NG1]);
    __syncthreads();

    for (int s = 0; s < T; ++s) {
        const int t = dir ? (T - 1 - s) : s;
        float z = xw_cur;
        if (s + 1 < T) {
            const int tn = dir ? (T - 2 - s) : (s + 1);
            xw_cur = __bfloat162float(xwp[(size_t)tn * NG1]);
        }
        const float4* h4 = (const float4*)hc_s[dir];
        #pragma unroll
        for (int k4 = 0; k4 < H1 / 4; ++k4) {
            const float4 v = h4[k4];
            z += v.x * Uc[4*k4] + v.y * Uc[4*k4+1] + v.z * Uc[4*k4+2] + v.w * Uc[4*k4+3];
        }
        z_s[dir][j] = z;
        __syncthreads();
        if (j < H1) {
            const float ig = sigmoidf_(z_s[dir][j]);
            const float fg = sigmoidf_(z_s[dir][H1 + j]);
            const float gg = tanhf_(z_s[dir][2*H1 + j]);
            const float og = sigmoidf_(z_s[dir][3*H1 + j]);
            c = fg * c + ig * gg;
            const float h = og * tanhf_(c);
            hc_s[dir][j] = h;
            h1p[(size_t)t * NH1 + dir * H1 + j] = __float2bfloat16(h);
        }
        __syncthreads();
    }
}

// ---------------- K3: xw2 = h1 @ [W2f|W2b] + bias -> bf16 [rows,128] ---------
__global__ __launch_bounds__(256, 4) void k3_xw2(
    const __hip_bfloat16* __restrict__ h1,  // [rows, NH1]
    const float* __restrict__ W2f, const float* __restrict__ b2f,
    const float* __restrict__ W2b, const float* __restrict__ b2b,
    __hip_bfloat16* __restrict__ xw2)       // [rows, NG2]
{
    __shared__ float x_s[32 * NH1];          // 8 KB fp32 (converted from bf16)
    const int tid  = threadIdx.x;
    const int row0 = blockIdx.x * 32;
    {   // stage 32x64 bf16 = 512 ushort4
        const ushort4* src = (const ushort4*)(h1 + (size_t)row0 * NH1);
        #pragma unroll
        for (int i = 0; i < 2; ++i) {
            const ushort4 u = src[tid + i * 256];
            const int base = (tid + i * 256) * 4;
            x_s[base + 0] = bfbits2f(u.x);
            x_s[base + 1] = bfbits2f(u.y);
            x_s[base + 2] = bfbits2f(u.z);
            x_s[base + 3] = bfbits2f(u.w);
        }
    }
    const int j  = tid & 127;            // gate column 0..127
    const int rh = tid >> 7;             // row half: rows [rh*16, rh*16+16)
    const float* Wcol;
    float bias;
    if (j < G2) { Wcol = W2f + j;        bias = b2f[j]; }
    else        { Wcol = W2b + (j - G2); bias = b2b[j - G2]; }

    float acc[16];
    #pragma unroll
    for (int r = 0; r < 16; ++r) acc[r] = bias;
    __syncthreads();

    for (int k4 = 0; k4 < NH1 / 4; ++k4) {
        const float w0 = Wcol[(4 * k4 + 0) * G2];
        const float w1 = Wcol[(4 * k4 + 1) * G2];
        const float w2 = Wcol[(4 * k4 + 2) * G2];
        const float w3 = Wcol[(4 * k4 + 3) * G2];
        #pragma unroll
        for (int r = 0; r < 16; ++r) {
            const float4 xv = ((const float4*)(x_s + (rh * 16 + r) * NH1))[k4];
            acc[r] += xv.x * w0 + xv.y * w1 + xv.z * w2 + xv.w * w3;
        }
    }
    #pragma unroll
    for (int r = 0; r < 16; ++r)
        xw2[(size_t)(row0 + rh * 16 + r) * NG2 + j] = __float2bfloat16(acc[r]);
}

// ---------------- K4: layer-2 bidirectional recurrence + dense head ----------
__global__ __launch_bounds__(128, 4) void k4_lstm2_head(
    const __hip_bfloat16* __restrict__ xw2,  // [chunkB*T, NG2]
    const float* __restrict__ U2f, const float* __restrict__ U2b,
    const float* __restrict__ W3, const float* __restrict__ b3,
    const float* __restrict__ W4, const float* __restrict__ b4,
    float* __restrict__ out)                 // [chunkB, 2]
{
    __shared__ float hc_s[2][H2];
    __shared__ float z_s[2][G2];
    __shared__ float y1_s[8];
    const int tid = threadIdx.x;
    const int dir = tid >> 6;
    const int j   = tid & 63;

    const __hip_bfloat16* xwp = xw2 + (size_t)blockIdx.x * T * NG2 + dir * G2 + j;
    const float* U2 = dir ? U2b : U2f;
    float Uc[H2];
    #pragma unroll
    for (int k = 0; k < H2; ++k) Uc[k] = U2[k * G2 + j];

    if (j < H2) hc_s[dir][j] = 0.0f;
    float c = 0.0f;

    int t0 = dir ? (T - 1) : 0;
    float xw_cur = __bfloat162float(xwp[(size_t)t0 * NG2]);
    __syncthreads();

    for (int s = 0; s < T; ++s) {
        float z = xw_cur;
        if (s + 1 < T) {
            const int tn = dir ? (T - 2 - s) : (s + 1);
            xw_cur = __bfloat162float(xwp[(size_t)tn * NG2]);
        }
        const float4* h4 = (const float4*)hc_s[dir];
        #pragma unroll
        for (int k4 = 0; k4 < H2 / 4; ++k4) {
            const float4 v = h4[k4];
            z += v.x * Uc[4*k4] + v.y * Uc[4*k4+1] + v.z * Uc[4*k4+2] + v.w * Uc[4*k4+3];
        }
        z_s[dir][j] = z;
        __syncthreads();
        if (j < H2) {
            const float ig = sigmoidf_(z_s[dir][j]);
            const float fg = sigmoidf_(z_s[dir][H2 + j]);
            const float gg = tanhf_(z_s[dir][2*H2 + j]);
            const float og = sigmoidf_(z_s[dir][3*H2 + j]);
            c = fg * c + ig * gg;
            hc_s[dir][j] = og * tanhf_(c);
        }
        __syncthreads();
    }

    // dense head: [h2f,h2b](32) @ W3(32x8)+b3 -> swish -> @W4(8x2)+b4 -> sigmoid
    if (tid < 8) {
        float acc = b3[tid];
        #pragma unroll
        for (int k = 0; k < 2 * H2; ++k) {
            const float v = (k < H2) ? hc_s[0][k] : hc_s[1][k - H2];
            acc += v * W3[k * 8 + tid];
        }
        y1_s[tid] = acc * sigmoidf_(acc);
    }
    __syncthreads();
    if (tid < 2) {
        float acc = b4[tid];
        #pragma unroll
        for (int k = 0; k < 8; ++k) acc += y1_s[k] * W4[k * 2 + tid];
        out[(size_t)blockIdx.x * 2 + tid] = sigmoidf_(acc);
    }
}

extern "C" void kernel_launch(void* const* d_in, const int* in_sizes, int n_in,
                              void* d_out, int out_size, void* d_ws, size_t ws_size,
                              hipStream_t stream) {
    const float* x   = (const float*)d_in[0];
    const float* W1f = (const float*)d_in[1];
    const float* U1f = (const float*)d_in[2];
    const float* b1f = (const float*)d_in[3];
    const float* W1b = (const float*)d_in[4];
    const float* U1b = (const float*)d_in[5];
    const float* b1b = (const float*)d_in[6];
    const float* W2f = (const float*)d_in[7];
    const float* U2f = (const float*)d_in[8];
    const float* b2f = (const float*)d_in[9];
    const float* W2b = (const float*)d_in[10];
    const float* U2b = (const float*)d_in[11];
    const float* b2b = (const float*)d_in[12];
    const float* W3  = (const float*)d_in[13];
    const float* b3  = (const float*)d_in[14];
    const float* W4  = (const float*)d_in[15];
    const float* b4  = (const float*)d_in[16];
    float* out = (float*)d_out;

    const int B = in_sizes[0] / (T * F);

    // ws layout (per chunk): region A = xw1 [chunkB*T,256] bf16, later reused
    // as xw2 [chunkB*T,128] bf16 (xw1 dead after K2); region B = h1 bf16.
    const size_t perA = (size_t)T * NG1 * sizeof(__hip_bfloat16);  // 64 KB/sample
    const size_t perB = (size_t)T * NH1 * sizeof(__hip_bfloat16);  // 16 KB/sample
    const size_t perS = perA + perB;                               // 80 KB/sample
    int chunkB = (int)(ws_size / perS);
    if (chunkB > B) chunkB = B;
    if (chunkB < 1) chunkB = 1;

    char* wsA = (char*)d_ws;
    char* wsB = wsA + (size_t)chunkB * perA;

    for (int b0 = 0; b0 < B; b0 += chunkB) {
        const int cb = (B - b0 < chunkB) ? (B - b0) : chunkB;
        const int nrows = cb * T;
        __hip_bfloat16* xw1 = (__hip_bfloat16*)wsA;
        __hip_bfloat16* h1  = (__hip_bfloat16*)wsB;
        __hip_bfloat16* xw2 = (__hip_bfloat16*)wsA;  // overlap: xw1 dead after K2

        k1_xw1<<<nrows / 32, 256, 0, stream>>>(
            x + (size_t)b0 * T * F, W1f, b1f, W1b, b1b, xw1);
        k2_lstm1<<<cb, 256, 0, stream>>>(xw1, U1f, U1b, h1);
        k3_xw2<<<nrows / 32, 256, 0, stream>>>(h1, W2f, b2f, W2b, b2b, xw2);
        k4_lstm2_head<<<cb, 128, 0, stream>>>(
            xw2, U2f, U2b, W3, b3, W4, b4, out + (size_t)b0 * 2);
    }
}

// Round 3
// 813.172 us; speedup vs baseline: 2.3067x; 1.5201x over previous
//
#include <hip/hip_runtime.h>
#include <hip/hip_bf16.h>

#define T 128
#define F 64
#define H1 32
#define G1 128   // 4*H1
#define H2 16
#define G2 64    // 4*H2
#define NG1 256  // both-dir gate width, layer 1
#define NG2 128  // both-dir gate width, layer 2
#define NH1 64   // concat h1 width

typedef __attribute__((ext_vector_type(8))) short bf16x8;
typedef __attribute__((ext_vector_type(4))) float f32x4;

#if __has_builtin(__builtin_amdgcn_fence)
#define WAVE_FENCE() __builtin_amdgcn_fence(__ATOMIC_ACQ_REL, "wavefront")
#else
#define WAVE_FENCE() __syncthreads()
#endif

__device__ __forceinline__ float sigmoidf_(float x) {
    return 1.0f / (1.0f + __expf(-x));
}
__device__ __forceinline__ float tanhf_(float x) {
    return 1.0f - 2.0f / (__expf(2.0f * x) + 1.0f);
}
__device__ __forceinline__ unsigned short f2bf(float f) {
    union { float f; unsigned u; } c; c.f = f;
    unsigned r = c.u + 0x7FFF + ((c.u >> 16) & 1);   // RTNE
    return (unsigned short)(r >> 16);
}
__device__ __forceinline__ float bf2f(unsigned short v) {
    union { unsigned u; float f; } c; c.u = ((unsigned)v) << 16; return c.f;
}

// ================= K1/K3: xW GEMM via MFMA bf16 ==============================
// out[rows, C] = bf16( x[rows,64] @ [Wa|Wb][64, C] + [ba|bb] )
// Block: 64 rows x C cols. 4 waves; wave w: dir half = (w<2)?a:b, local col
// range lb = (w&1)*(C/4). M-tiles 4, N-tiles C/64 per wave, K-steps 2.
template<int C, bool XF32>
__global__ __launch_bounds__(256) void gemm_xw_mfma(
    const void* __restrict__ xin,
    const float* __restrict__ Wa, const float* __restrict__ ba,
    const float* __restrict__ Wb, const float* __restrict__ bb,
    unsigned short* __restrict__ out)
{
    constexpr int NTPW = C / 64;   // N-tiles per wave (4 for C=256, 2 for C=128)
    constexpr int G = C / 2;       // per-direction width (leading dim of W)
    __shared__ unsigned short a_s[64 * 72];   // 64 rows x 64 k, row-padded to 72

    const int tid  = threadIdx.x;
    const int lane = tid & 63;
    const int w    = tid >> 6;
    const int row0 = blockIdx.x * 64;
    const int n15  = lane & 15;
    const int quad = lane >> 4;

    // ---- stage A (x) into LDS as bf16 [64][72] ----
    if constexpr (XF32) {
        const float4* src = (const float4*)((const float*)xin + (size_t)row0 * 64);
        #pragma unroll
        for (int i = 0; i < 4; ++i) {
            const int idx4 = i * 256 + tid;      // float4 idx in [0,1024)
            const float4 v = src[idx4];
            const int r  = idx4 >> 4;            // 16 float4 per row
            const int c4 = idx4 & 15;
            const unsigned lo = f2bf(v.x) | ((unsigned)f2bf(v.y) << 16);
            const unsigned hi = f2bf(v.z) | ((unsigned)f2bf(v.w) << 16);
            *((uint2*)(a_s + r * 72 + c4 * 4)) = make_uint2(lo, hi);
        }
    } else {
        const ushort4* src = (const ushort4*)((const unsigned short*)xin + (size_t)row0 * 64);
        #pragma unroll
        for (int i = 0; i < 4; ++i) {
            const int idx4 = i * 256 + tid;      // ushort4 idx in [0,1024)
            const ushort4 v = src[idx4];
            const int r  = idx4 >> 4;
            const int c4 = idx4 & 15;
            *((ushort4*)(a_s + r * 72 + c4 * 4)) = v;
        }
    }

    // ---- B fragments + bias, straight from global (L2-hot, coalesced) ----
    const float* Wsel = (w < 2) ? Wa : Wb;
    const float* bsel = (w < 2) ? ba : bb;
    const int lb = (w & 1) * (NTPW * 16);

    bf16x8 Bfrag[NTPW][2];
    float bias[NTPW];
    #pragma unroll
    for (int nt = 0; nt < NTPW; ++nt) {
        const int n = lb + nt * 16 + n15;
        bias[nt] = bsel[n];
        #pragma unroll
        for (int ks = 0; ks < 2; ++ks) {
            bf16x8 f;
            #pragma unroll
            for (int j = 0; j < 8; ++j) {
                const int k = ks * 32 + quad * 8 + j;
                f[j] = (short)f2bf(Wsel[k * G + n]);
            }
            Bfrag[nt][ks] = f;
        }
    }
    __syncthreads();

    // ---- MFMA main loop ----
    f32x4 acc[4][NTPW];
    #pragma unroll
    for (int mt = 0; mt < 4; ++mt)
        #pragma unroll
        for (int nt = 0; nt < NTPW; ++nt)
            acc[mt][nt] = (f32x4)0.0f;

    #pragma unroll
    for (int ks = 0; ks < 2; ++ks) {
        #pragma unroll
        for (int mt = 0; mt < 4; ++mt) {
            const bf16x8 afrag = *((const bf16x8*)(a_s + (mt * 16 + n15) * 72 + ks * 32 + quad * 8));
            #pragma unroll
            for (int nt = 0; nt < NTPW; ++nt)
                acc[mt][nt] = __builtin_amdgcn_mfma_f32_16x16x32_bf16(
                    afrag, Bfrag[nt][ks], acc[mt][nt], 0, 0, 0);
        }
    }

    // ---- epilogue: +bias, cvt bf16, store ----
    const int coldir = (w < 2) ? 0 : G;
    #pragma unroll
    for (int mt = 0; mt < 4; ++mt) {
        #pragma unroll
        for (int nt = 0; nt < NTPW; ++nt) {
            const int col = coldir + lb + nt * 16 + n15;
            const f32x4 a = acc[mt][nt];
            #pragma unroll
            for (int r = 0; r < 4; ++r) {
                const int row = row0 + mt * 16 + quad * 4 + r;
                out[(size_t)row * C + col] = f2bf(a[r] + bias[nt]);
            }
        }
    }
}

// ================= K2: layer-1 recurrence, wave-synchronous ==================
// Wave = (sample, dir). Lane owns gate cols j0=2*lane, j0+1. U cols in explicit
// float2 scalars (no arrays -> no scratch). No __syncthreads in the loop.
__global__ __launch_bounds__(256) void lstm1_rec(
    const unsigned short* __restrict__ xw1,  // [cb*T, 256] bf16 bits
    const float* __restrict__ U1f, const float* __restrict__ U1b,
    unsigned short* __restrict__ h1)         // [cb*T, 64]
{
    __shared__ float z_s[4][G1];
    __shared__ float h_s[4][H1];
    const int tid  = threadIdx.x;
    const int lane = tid & 63;
    const int w    = tid >> 6;
    const int dir  = w & 1;
    const int sample = blockIdx.x * 2 + (w >> 1);
    const float* U = dir ? U1b : U1f;
    const int j0 = 2 * lane;

#define LDU1(i) \
    const float2 u##i##_0 = *(const float2*)(U + (4*i+0)*G1 + j0); \
    const float2 u##i##_1 = *(const float2*)(U + (4*i+1)*G1 + j0); \
    const float2 u##i##_2 = *(const float2*)(U + (4*i+2)*G1 + j0); \
    const float2 u##i##_3 = *(const float2*)(U + (4*i+3)*G1 + j0);
    LDU1(0) LDU1(1) LDU1(2) LDU1(3) LDU1(4) LDU1(5) LDU1(6) LDU1(7)
#undef LDU1

    float* zs = z_s[w];
    float* hs = h_s[w];
    if (lane < H1) hs[lane] = 0.0f;
    float c = 0.0f;

    const unsigned short* xwp = xw1 + (size_t)sample * T * NG1 + dir * G1 + j0;
    unsigned short* h1p = h1 + (size_t)sample * T * NH1 + dir * H1;

    int t = dir ? (T - 1) : 0;
    const int tstep = dir ? -1 : 1;
    unsigned cur = *(const unsigned*)(xwp + (size_t)t * NG1);
    WAVE_FENCE();

    #pragma unroll 1
    for (int s = 0; s < T; ++s) {
        const int tcur = t;
        t += tstep;
        float z0 = bf2f((unsigned short)(cur & 0xffffu));
        float z1 = bf2f((unsigned short)(cur >> 16));
        if (s + 1 < T) cur = *(const unsigned*)(xwp + (size_t)t * NG1);

#define ACC1(i) { const float4 hv = *(const float4*)(hs + 4*i); \
        z0 += hv.x*u##i##_0.x + hv.y*u##i##_1.x + hv.z*u##i##_2.x + hv.w*u##i##_3.x; \
        z1 += hv.x*u##i##_0.y + hv.y*u##i##_1.y + hv.z*u##i##_2.y + hv.w*u##i##_3.y; }
        ACC1(0) ACC1(1) ACC1(2) ACC1(3) ACC1(4) ACC1(5) ACC1(6) ACC1(7)
#undef ACC1

        *((float2*)(zs + j0)) = make_float2(z0, z1);
        WAVE_FENCE();
        if (lane < H1) {
            const float ig = sigmoidf_(zs[lane]);
            const float fg = sigmoidf_(zs[H1 + lane]);
            const float gg = tanhf_(zs[2*H1 + lane]);
            const float og = sigmoidf_(zs[3*H1 + lane]);
            c = fg * c + ig * gg;
            const float h = og * tanhf_(c);
            hs[lane] = h;
            h1p[(size_t)tcur * NH1 + lane] = f2bf(h);
        }
        WAVE_FENCE();
    }
}

// ================= K4: layer-2 recurrence + dense head =======================
__global__ __launch_bounds__(256) void lstm2_head(
    const unsigned short* __restrict__ xw2,  // [cb*T, 128] bf16 bits
    const float* __restrict__ U2f, const float* __restrict__ U2b,
    const float* __restrict__ W3, const float* __restrict__ b3,
    const float* __restrict__ W4, const float* __restrict__ b4,
    float* __restrict__ out)                 // [cb, 2]
{
    __shared__ float z_s[4][G2];
    __shared__ float h_s[4][H2];
    __shared__ float h2_s[2][2][H2];
    __shared__ float y_s[2][8];
    const int tid  = threadIdx.x;
    const int lane = tid & 63;
    const int w    = tid >> 6;
    const int dir  = w & 1;
    const int sl   = w >> 1;
    const int sample = blockIdx.x * 2 + sl;
    const float* U = dir ? U2b : U2f;
    const int j = lane;

#define LDU2(i) const float uu##i = U[i * G2 + j];
    LDU2(0) LDU2(1) LDU2(2) LDU2(3) LDU2(4) LDU2(5) LDU2(6) LDU2(7)
    LDU2(8) LDU2(9) LDU2(10) LDU2(11) LDU2(12) LDU2(13) LDU2(14) LDU2(15)
#undef LDU2

    float* zs = z_s[w];
    float* hs = h_s[w];
    if (lane < H2) hs[lane] = 0.0f;
    float c = 0.0f;

    const unsigned short* xwp = xw2 + (size_t)sample * T * NG2 + dir * G2 + j;
    int t = dir ? (T - 1) : 0;
    const int tstep = dir ? -1 : 1;
    unsigned short cur = xwp[(size_t)t * NG2];
    WAVE_FENCE();

    #pragma unroll 1
    for (int s = 0; s < T; ++s) {
        t += tstep;
        float z = bf2f(cur);
        if (s + 1 < T) cur = xwp[(size_t)t * NG2];
        { const float4 hv = *(const float4*)(hs + 0);  z += hv.x*uu0  + hv.y*uu1  + hv.z*uu2  + hv.w*uu3;  }
        { const float4 hv = *(const float4*)(hs + 4);  z += hv.x*uu4  + hv.y*uu5  + hv.z*uu6  + hv.w*uu7;  }
        { const float4 hv = *(const float4*)(hs + 8);  z += hv.x*uu8  + hv.y*uu9  + hv.z*uu10 + hv.w*uu11; }
        { const float4 hv = *(const float4*)(hs + 12); z += hv.x*uu12 + hv.y*uu13 + hv.z*uu14 + hv.w*uu15; }
        zs[j] = z;
        WAVE_FENCE();
        if (lane < H2) {
            const float ig = sigmoidf_(zs[lane]);
            const float fg = sigmoidf_(zs[H2 + lane]);
            const float gg = tanhf_(zs[2*H2 + lane]);
            const float og = sigmoidf_(zs[3*H2 + lane]);
            c = fg * c + ig * gg;
            hs[lane] = og * tanhf_(c);
        }
        WAVE_FENCE();
    }

    if (lane < H2) h2_s[sl][dir][lane] = hs[lane];
    __syncthreads();

    if (tid < 16) {
        const int s = tid >> 3, u = tid & 7;
        float a = b3[u];
        #pragma unroll
        for (int k = 0; k < H2; ++k) a += h2_s[s][0][k] * W3[k * 8 + u];
        #pragma unroll
        for (int k = 0; k < H2; ++k) a += h2_s[s][1][k] * W3[(H2 + k) * 8 + u];
        y_s[s][u] = a * sigmoidf_(a);
    }
    __syncthreads();
    if (tid < 4) {
        const int s = tid >> 1, o = tid & 1;
        float a = b4[o];
        #pragma unroll
        for (int k = 0; k < 8; ++k) a += y_s[s][k] * W4[k * 2 + o];
        out[(size_t)(blockIdx.x * 2 + s) * 2 + o] = sigmoidf_(a);
    }
}

extern "C" void kernel_launch(void* const* d_in, const int* in_sizes, int n_in,
                              void* d_out, int out_size, void* d_ws, size_t ws_size,
                              hipStream_t stream) {
    const float* x   = (const float*)d_in[0];
    const float* W1f = (const float*)d_in[1];
    const float* U1f = (const float*)d_in[2];
    const float* b1f = (const float*)d_in[3];
    const float* W1b = (const float*)d_in[4];
    const float* U1b = (const float*)d_in[5];
    const float* b1b = (const float*)d_in[6];
    const float* W2f = (const float*)d_in[7];
    const float* U2f = (const float*)d_in[8];
    const float* b2f = (const float*)d_in[9];
    const float* W2b = (const float*)d_in[10];
    const float* U2b = (const float*)d_in[11];
    const float* b2b = (const float*)d_in[12];
    const float* W3  = (const float*)d_in[13];
    const float* b3  = (const float*)d_in[14];
    const float* W4  = (const float*)d_in[15];
    const float* b4  = (const float*)d_in[16];
    float* out = (float*)d_out;

    const int B = in_sizes[0] / (T * F);

    // ws: region A = xw1 [cb*T,256] bf16 (reused as xw2 [cb*T,128]); B = h1.
    const size_t perA = (size_t)T * NG1 * sizeof(unsigned short);  // 64 KB/sample
    const size_t perB = (size_t)T * NH1 * sizeof(unsigned short);  // 16 KB/sample
    int chunkB = (int)(ws_size / (perA + perB));
    chunkB &= ~1;                       // even: k2/k4 blocks cover 2 samples
    if (chunkB > B) chunkB = B;
    if (chunkB < 2) chunkB = 2;

    char* wsA = (char*)d_ws;
    char* wsB = wsA + (size_t)chunkB * perA;

    for (int b0 = 0; b0 < B; b0 += chunkB) {
        const int cb = (B - b0 < chunkB) ? (B - b0) : chunkB;
        const int nrows = cb * T;
        unsigned short* xw1 = (unsigned short*)wsA;
        unsigned short* h1  = (unsigned short*)wsB;
        unsigned short* xw2 = (unsigned short*)wsA;  // xw1 dead after K2

        gemm_xw_mfma<NG1, true><<<nrows / 64, 256, 0, stream>>>(
            (const void*)(x + (size_t)b0 * T * F), W1f, b1f, W1b, b1b, xw1);
        lstm1_rec<<<cb / 2, 256, 0, stream>>>(xw1, U1f, U1b, h1);
        gemm_xw_mfma<NG2, false><<<nrows / 64, 256, 0, stream>>>(
            (const void*)h1, W2f, b2f, W2b, b2b, xw2);
        lstm2_head<<<cb / 2, 256, 0, stream>>>(
            xw2, U2f, U2b, W3, b3, W4, b4, out + (size_t)b0 * 2);
    }
}

// Round 4
// 678.430 us; speedup vs baseline: 2.7648x; 1.1986x over previous
//
#include <hip/hip_runtime.h>
#include <hip/hip_bf16.h>

#define T 128
#define F 64
#define H1 32
#define G1 128   // 4*H1
#define H2 16
#define G2 64    // 4*H2
#define NG1 256  // both-dir gate width, layer 1
#define NG2 128  // both-dir gate width, layer 2
#define NH1 64   // concat h1 width

typedef __attribute__((ext_vector_type(8))) short bf16x8;
typedef __attribute__((ext_vector_type(4))) float f32x4;

#if __has_builtin(__builtin_amdgcn_fence)
#define WAVE_FENCE() __builtin_amdgcn_fence(__ATOMIC_ACQ_REL, "wavefront")
#else
#define WAVE_FENCE() __syncthreads()
#endif

__device__ __forceinline__ float sigmoidf_(float x) {
    return 1.0f / (1.0f + __expf(-x));
}
__device__ __forceinline__ float tanhf_(float x) {
    return 1.0f - 2.0f / (__expf(2.0f * x) + 1.0f);
}
__device__ __forceinline__ unsigned short f2bf(float f) {
    union { float f; unsigned u; } c; c.f = f;
    unsigned r = c.u + 0x7FFF + ((c.u >> 16) & 1);   // RTNE
    return (unsigned short)(r >> 16);
}
__device__ __forceinline__ float bflo(unsigned u) {
    union { unsigned x; float f; } c; c.x = u << 16; return c.f;
}
__device__ __forceinline__ float bfhi(unsigned u) {
    union { unsigned x; float f; } c; c.x = u & 0xffff0000u; return c.f;
}

// =============================================================================
// K1/K3: xW GEMM, M tiled over SAMPLES at fixed t; output written in the
// per-lane-packed layout the recurrence kernels consume:
//   per (g = sample-group-of-16, t, d): 64 lanes x (4*NGATE_FRAGS) bf16,
//   slot (frag*4 + r) at lane*(G/4) shorts. C-fragment order == MFMA C layout.
// =============================================================================
template<int C, bool XF32>
__global__ __launch_bounds__(256) void gemm_xw_packed(
    const void* __restrict__ xin,     // XF32: fp32 [s][T][64]; else bf16 h1 [g*T+t][16][64]
    const float* __restrict__ Wa, const float* __restrict__ ba,
    const float* __restrict__ Wb, const float* __restrict__ bb,
    unsigned short* __restrict__ outp)
{
    constexpr int G   = C / 2;    // cols per direction (128 or 64)
    constexpr int NTL = C / 64;   // n-tiles per wave (4 or 2)
    __shared__ unsigned short a_s[64 * 72];

    const int tid  = threadIdx.x;
    const int lane = tid & 63;
    const int w    = tid >> 6;
    const int n15  = lane & 15, quad = lane >> 4;
    const int sb   = blockIdx.x;          // block of 64 samples
    const int t    = blockIdx.y;
    const int g0   = sb * 4;              // sample-group base

    // ---- stage A: 64 samples x 64 k (bf16, row-padded to 72) ----
    if constexpr (XF32) {
        const float* x = (const float*)xin;
        #pragma unroll
        for (int i = 0; i < 4; ++i) {
            const int idx = tid + i * 256;            // float4 index 0..1023
            const int row = idx >> 4, c4 = idx & 15;
            const float4 v = *(const float4*)(x + ((size_t)(sb * 64 + row) * T + t) * 64 + c4 * 4);
            ushort4 u;
            u.x = f2bf(v.x); u.y = f2bf(v.y); u.z = f2bf(v.z); u.w = f2bf(v.w);
            *(ushort4*)(a_s + row * 72 + c4 * 4) = u;
        }
    } else {
        const unsigned short* h = (const unsigned short*)xin;
        #pragma unroll
        for (int i = 0; i < 2; ++i) {
            const int idx = tid + i * 256;            // 16B chunk index 0..511
            const int row = idx >> 3, off = idx & 7;
            const uint4 v = *(const uint4*)(h + ((size_t)(g0 + (row >> 4)) * T + t) * 1024
                                              + (row & 15) * 64 + off * 8);
            *(uint4*)(a_s + row * 72 + off * 8) = v;
        }
    }

    const int d  = w >> 1;
    const int lb = (w & 1) * (NTL * 16);
    const float* Wsel = d ? Wb : Wa;
    const float* bsel = d ? bb : ba;

    bf16x8 Bf[NTL][2];
    float bias[NTL];
    #pragma unroll
    for (int ntl = 0; ntl < NTL; ++ntl) {
        const int n = lb + ntl * 16 + n15;
        bias[ntl] = bsel[n];
        #pragma unroll
        for (int ks = 0; ks < 2; ++ks) {
            bf16x8 f;
            #pragma unroll
            for (int j = 0; j < 8; ++j)
                f[j] = (short)f2bf(Wsel[(ks * 32 + quad * 8 + j) * G + n]);
            Bf[ntl][ks] = f;
        }
    }
    __syncthreads();

    f32x4 acc[4][NTL];
    #pragma unroll
    for (int mt = 0; mt < 4; ++mt)
        #pragma unroll
        for (int ntl = 0; ntl < NTL; ++ntl)
            acc[mt][ntl] = (f32x4)0.0f;

    #pragma unroll
    for (int ks = 0; ks < 2; ++ks) {
        #pragma unroll
        for (int mt = 0; mt < 4; ++mt) {
            const bf16x8 af = *(const bf16x8*)(a_s + (mt * 16 + n15) * 72 + ks * 32 + quad * 8);
            #pragma unroll
            for (int ntl = 0; ntl < NTL; ++ntl)
                acc[mt][ntl] = __builtin_amdgcn_mfma_f32_16x16x32_bf16(
                    af, Bf[ntl][ks], acc[mt][ntl], 0, 0, 0);
        }
    }

    // ---- packed epilogue ----
    #pragma unroll
    for (int mt = 0; mt < 4; ++mt) {
        const int g = g0 + mt;
        unsigned short* dst = outp + (((size_t)g * T + t) * 2 + d) * (16 * G)
                                   + lane * (G / 4) + (w & 1) * (NTL * 4);
        unsigned tw[NTL * 2];
        #pragma unroll
        for (int ntl = 0; ntl < NTL; ++ntl) {
            const unsigned lo0 = f2bf(acc[mt][ntl][0] + bias[ntl]);
            const unsigned hi0 = f2bf(acc[mt][ntl][1] + bias[ntl]);
            const unsigned lo1 = f2bf(acc[mt][ntl][2] + bias[ntl]);
            const unsigned hi1 = f2bf(acc[mt][ntl][3] + bias[ntl]);
            tw[ntl * 2 + 0] = lo0 | (hi0 << 16);
            tw[ntl * 2 + 1] = lo1 | (hi1 << 16);
        }
        #pragma unroll
        for (int q = 0; q < (NTL * 2) / 4; ++q)
            *(uint4*)(dst + q * 8) = *(uint4*)(tw + q * 4);
    }
}

// =============================================================================
// K2: layer-1 recurrence, 16 samples per wave, MFMA recurrent matvec.
// Block = 1 wave = (sample-group g, dir d).
// =============================================================================
__global__ __launch_bounds__(64) void lstm1_rec_mfma(
    const unsigned short* __restrict__ xw1,   // packed [g][t][d]: lane*32 shorts
    const float* __restrict__ U1f, const float* __restrict__ U1b,
    unsigned short* __restrict__ h1)          // [g*T+t][16][64]
{
    __shared__ unsigned short hbuf[16 * 32];  // [m][k] bf16
    const int lane = threadIdx.x;
    const int n15 = lane & 15, quad = lane >> 4;
    const int d = blockIdx.x & 1, g = blockIdx.x >> 1;
    const float* U = d ? U1b : U1f;

    bf16x8 Uf[8];
    #pragma unroll
    for (int nt = 0; nt < 8; ++nt) {
        bf16x8 f;
        #pragma unroll
        for (int j = 0; j < 8; ++j)
            f[j] = (short)f2bf(U[(quad * 8 + j) * G1 + nt * 16 + n15]);
        Uf[nt] = f;
    }

    *(uint4*)(hbuf + lane * 8) = (uint4){0, 0, 0, 0};   // h0 = 0
    f32x4 c0 = (f32x4)0.0f, c1 = (f32x4)0.0f;

    const unsigned short* xl = xw1 + ((size_t)g * T * 2 + d) * 2048 + lane * 32;
    const size_t stepS = 2 * 2048;   // shorts per t

    uint4 xbA[4], xbB[4];
    {
        const unsigned short* p0 = xl + (size_t)(d ? (T - 1) : 0) * stepS;
        xbA[0] = *(const uint4*)(p0);      xbA[1] = *(const uint4*)(p0 + 8);
        xbA[2] = *(const uint4*)(p0 + 16); xbA[3] = *(const uint4*)(p0 + 24);
        const unsigned short* p1 = xl + (size_t)(d ? (T - 2) : 1) * stepS;
        xbB[0] = *(const uint4*)(p1);      xbB[1] = *(const uint4*)(p1 + 8);
        xbB[2] = *(const uint4*)(p1 + 16); xbB[3] = *(const uint4*)(p1 + 24);
    }
    WAVE_FENCE();

    auto step = [&](int s, uint4 (&xb)[4]) {
        const int t = d ? (T - 1 - s) : s;
        // acc init from packed xw (slot f*4+r)
        f32x4 acc[8];
        #pragma unroll
        for (int f = 0; f < 8; ++f) {
            const uint4 q = xb[f >> 1];
            const unsigned lo = (f & 1) ? q.z : q.x;
            const unsigned hi = (f & 1) ? q.w : q.y;
            acc[f][0] = bflo(lo); acc[f][1] = bfhi(lo);
            acc[f][2] = bflo(hi); acc[f][3] = bfhi(hi);
        }
        // prefetch t(s+2)
        if (s + 2 < T) {
            const unsigned short* pn = xl + (size_t)(d ? (T - 3 - s) : (s + 2)) * stepS;
            xb[0] = *(const uint4*)(pn);      xb[1] = *(const uint4*)(pn + 8);
            xb[2] = *(const uint4*)(pn + 16); xb[3] = *(const uint4*)(pn + 24);
        }
        // recurrent matvec
        const bf16x8 af = *(const bf16x8*)(hbuf + n15 * 32 + quad * 8);
        #pragma unroll
        for (int f = 0; f < 8; ++f)
            acc[f] = __builtin_amdgcn_mfma_f32_16x16x32_bf16(af, Uf[f], acc[f], 0, 0, 0);
        // cell update: lane owns cols n15 (nt=0) and 16+n15 (nt=1), rows quad*4+r
        float hv[2][4];
        #pragma unroll
        for (int nt = 0; nt < 2; ++nt) {
            f32x4& cc = nt ? c1 : c0;
            #pragma unroll
            for (int r = 0; r < 4; ++r) {
                const float ig = sigmoidf_(acc[nt][r]);
                const float fg = sigmoidf_(acc[2 + nt][r]);
                const float gg = tanhf_(acc[4 + nt][r]);
                const float og = sigmoidf_(acc[6 + nt][r]);
                cc[r] = fg * cc[r] + ig * gg;
                hv[nt][r] = og * tanhf_(cc[r]);
            }
        }
        WAVE_FENCE();
        #pragma unroll
        for (int nt = 0; nt < 2; ++nt)
            #pragma unroll
            for (int r = 0; r < 4; ++r)
                hbuf[(quad * 4 + r) * 32 + nt * 16 + n15] = f2bf(hv[nt][r]);
        WAVE_FENCE();
        // coalesced h1 write: lane -> (row=lane>>2, chunk=lane&3)
        const uint4 hh = *(const uint4*)(hbuf + (lane >> 2) * 32 + (lane & 3) * 8);
        *(uint4*)(h1 + ((size_t)g * T + t) * 1024 + (lane >> 2) * 64 + d * 32 + (lane & 3) * 8) = hh;
        WAVE_FENCE();
    };

    #pragma unroll 1
    for (int s = 0; s < T; s += 2) {
        step(s, xbA);
        step(s + 1, xbB);
    }
}

// =============================================================================
// K4: layer-2 recurrence (16 samples/wave, K=16 zero-padded) + dense head.
// Block = 128 threads = fwd wave + bwd wave of one sample-group.
// =============================================================================
__global__ __launch_bounds__(128) void lstm2_head_mfma(
    const unsigned short* __restrict__ xw2,   // packed [g][t][d]: lane*16 shorts
    const float* __restrict__ U2f, const float* __restrict__ U2b,
    const float* __restrict__ W3, const float* __restrict__ b3,
    const float* __restrict__ W4, const float* __restrict__ b4,
    float* __restrict__ out)                  // [16 samples][2] per block
{
    __shared__ unsigned short hbuf[2][16 * 16];
    __shared__ float hfin[2][16][16];
    __shared__ float ybuf[16][9];
    const int tid  = threadIdx.x;
    const int lane = tid & 63;
    const int d    = tid >> 6;
    const int n15  = lane & 15, quad = lane >> 4;
    const int g    = blockIdx.x;
    const float* U = d ? U2b : U2f;

    bf16x8 Uf[4];
    #pragma unroll
    for (int nt = 0; nt < 4; ++nt) {
        bf16x8 f;
        #pragma unroll
        for (int j = 0; j < 8; ++j) {
            const int k = quad * 8 + j;
            f[j] = (k < H2) ? (short)f2bf(U[k * G2 + nt * 16 + n15]) : (short)0;
        }
        Uf[nt] = f;
    }

    *(uint2*)(hbuf[d] + lane * 4) = (uint2){0, 0};
    f32x4 c = (f32x4)0.0f;
    float hlast[4] = {0.f, 0.f, 0.f, 0.f};

    const unsigned short* xl = xw2 + ((size_t)g * T * 2 + d) * 1024 + lane * 16;
    const size_t stepS = 2 * 1024;

    uint4 xbA[2], xbB[2];
    {
        const unsigned short* p0 = xl + (size_t)(d ? (T - 1) : 0) * stepS;
        xbA[0] = *(const uint4*)(p0); xbA[1] = *(const uint4*)(p0 + 8);
        const unsigned short* p1 = xl + (size_t)(d ? (T - 2) : 1) * stepS;
        xbB[0] = *(const uint4*)(p1); xbB[1] = *(const uint4*)(p1 + 8);
    }
    WAVE_FENCE();

    auto step = [&](int s, uint4 (&xb)[2]) {
        f32x4 acc[4];
        #pragma unroll
        for (int f = 0; f < 4; ++f) {
            const uint4 q = xb[f >> 1];
            const unsigned lo = (f & 1) ? q.z : q.x;
            const unsigned hi = (f & 1) ? q.w : q.y;
            acc[f][0] = bflo(lo); acc[f][1] = bfhi(lo);
            acc[f][2] = bflo(hi); acc[f][3] = bfhi(hi);
        }
        if (s + 2 < T) {
            const unsigned short* pn = xl + (size_t)(d ? (T - 3 - s) : (s + 2)) * stepS;
            xb[0] = *(const uint4*)(pn); xb[1] = *(const uint4*)(pn + 8);
        }
        bf16x8 af = (bf16x8)(short)0;
        if (quad < 2) af = *(const bf16x8*)(hbuf[d] + n15 * 16 + quad * 8);
        #pragma unroll
        for (int f = 0; f < 4; ++f)
            acc[f] = __builtin_amdgcn_mfma_f32_16x16x32_bf16(af, Uf[f], acc[f], 0, 0, 0);
        // gates: i=acc0, f=acc1, g=acc2, o=acc3 (col n15, rows quad*4+r)
        #pragma unroll
        for (int r = 0; r < 4; ++r) {
            const float ig = sigmoidf_(acc[0][r]);
            const float fg = sigmoidf_(acc[1][r]);
            const float gg = tanhf_(acc[2][r]);
            const float og = sigmoidf_(acc[3][r]);
            c[r] = fg * c[r] + ig * gg;
            hlast[r] = og * tanhf_(c[r]);
        }
        WAVE_FENCE();
        #pragma unroll
        for (int r = 0; r < 4; ++r)
            hbuf[d][(quad * 4 + r) * 16 + n15] = f2bf(hlast[r]);
        WAVE_FENCE();
    };

    #pragma unroll 1
    for (int s = 0; s < T; s += 2) {
        step(s, xbA);
        step(s + 1, xbB);
    }

    #pragma unroll
    for (int r = 0; r < 4; ++r)
        hfin[d][quad * 4 + r][n15] = hlast[r];
    __syncthreads();

    // head: y = swish([h2f,h2b] @ W3 + b3); out = sigmoid(y @ W4 + b4)
    {
        const int s = tid >> 3, u = tid & 7;      // 16 samples x 8 units
        float a = b3[u];
        #pragma unroll
        for (int k = 0; k < H2; ++k) a += hfin[0][s][k] * W3[k * 8 + u];
        #pragma unroll
        for (int k = 0; k < H2; ++k) a += hfin[1][s][k] * W3[(H2 + k) * 8 + u];
        ybuf[s][u] = a * sigmoidf_(a);
    }
    __syncthreads();
    if (tid < 32) {
        const int s = tid >> 1, o = tid & 1;
        float a = b4[o];
        #pragma unroll
        for (int k = 0; k < 8; ++k) a += ybuf[s][k] * W4[k * 2 + o];
        out[(size_t)(g * 16 + s) * 2 + o] = sigmoidf_(a);
    }
}

extern "C" void kernel_launch(void* const* d_in, const int* in_sizes, int n_in,
                              void* d_out, int out_size, void* d_ws, size_t ws_size,
                              hipStream_t stream) {
    const float* x   = (const float*)d_in[0];
    const float* W1f = (const float*)d_in[1];
    const float* U1f = (const float*)d_in[2];
    const float* b1f = (const float*)d_in[3];
    const float* W1b = (const float*)d_in[4];
    const float* U1b = (const float*)d_in[5];
    const float* b1b = (const float*)d_in[6];
    const float* W2f = (const float*)d_in[7];
    const float* U2f = (const float*)d_in[8];
    const float* b2f = (const float*)d_in[9];
    const float* W2b = (const float*)d_in[10];
    const float* U2b = (const float*)d_in[11];
    const float* b2b = (const float*)d_in[12];
    const float* W3  = (const float*)d_in[13];
    const float* b3  = (const float*)d_in[14];
    const float* W4  = (const float*)d_in[15];
    const float* b4  = (const float*)d_in[16];
    float* out = (float*)d_out;

    const int B = in_sizes[0] / (T * F);

    // ws: region A = packed xw1 (64 KB/sample), reused as packed xw2 (32 KB/s);
    //     region B = h1 [g*T+t][16][64] bf16 (16 KB/sample).
    const size_t perA = 65536, perB = 16384;
    int chunkB = (int)(ws_size / (perA + perB));
    chunkB &= ~63;                       // k1/k3 blocks cover 64 samples
    if (chunkB > B) chunkB = B;
    if (chunkB < 64) chunkB = 64;

    char* wsA = (char*)d_ws;
    char* wsB = wsA + (size_t)chunkB * perA;

    for (int b0 = 0; b0 < B; b0 += chunkB) {
        const int cb = (B - b0 < chunkB) ? (B - b0) : chunkB;
        unsigned short* xw1 = (unsigned short*)wsA;
        unsigned short* h1  = (unsigned short*)wsB;
        unsigned short* xw2 = (unsigned short*)wsA;   // xw1 dead after K2

        dim3 gg(cb / 64, T);
        gemm_xw_packed<NG1, true><<<gg, 256, 0, stream>>>(
            (const void*)(x + (size_t)b0 * T * F), W1f, b1f, W1b, b1b, xw1);
        lstm1_rec_mfma<<<(cb / 16) * 2, 64, 0, stream>>>(xw1, U1f, U1b, h1);
        gemm_xw_packed<NG2, false><<<gg, 256, 0, stream>>>(
            (const void*)h1, W2f, b2f, W2b, b2b, xw2);
        lstm2_head_mfma<<<cb / 16, 128, 0, stream>>>(
            xw2, U2f, U2b, W3, b3, W4, b4, out + (size_t)b0 * 2);
    }
}

// Round 5
// 528.399 us; speedup vs baseline: 3.5499x; 1.2839x over previous
//
#include <hip/hip_runtime.h>
#include <hip/hip_bf16.h>

#define T 128
#define F 64
#define H1 32
#define G1 128   // 4*H1
#define H2 16
#define G2 64    // 4*H2
#define NH1 64   // concat h1 width

typedef __attribute__((ext_vector_type(8))) short bf16x8;
typedef __attribute__((ext_vector_type(4))) float f32x4;

__device__ __forceinline__ float sigmoidf_(float x) {
    return 1.0f / (1.0f + __expf(-x));
}
__device__ __forceinline__ float tanhf_(float x) {
    return 1.0f - 2.0f / (__expf(2.0f * x) + 1.0f);
}
__device__ __forceinline__ unsigned short f2bf(float f) {
    union { float f; unsigned u; } c; c.f = f;
    unsigned r = c.u + 0x7FFF + ((c.u >> 16) & 1);   // RTNE
    return (unsigned short)(r >> 16);
}
// CK-style LDS-only barrier: waits DS ops, does NOT drain vmcnt (keeps the
// global prefetch pipeline alive across the per-step sync).
__device__ __forceinline__ void lds_barrier() {
    asm volatile("s_waitcnt lgkmcnt(0)" ::: "memory");
    __builtin_amdgcn_s_barrier();
}
__device__ __forceinline__ bf16x8 pack8(float4 a, float4 b) {
    bf16x8 f;
    f[0] = (short)f2bf(a.x); f[1] = (short)f2bf(a.y);
    f[2] = (short)f2bf(a.z); f[3] = (short)f2bf(a.w);
    f[4] = (short)f2bf(b.x); f[5] = (short)f2bf(b.y);
    f[6] = (short)f2bf(b.z); f[7] = (short)f2bf(b.w);
    return f;
}

// =============================================================================
// K1: layer-1 recurrence with fused x@W1, 16 samples per block, 2 waves.
// Block = (sample-group g, dir d); wave wv owns gate-frags {2i+wv}, i=i,f,g,o.
// Per step: z = bias + x_t@W1 (2 MFMA/frag) + h@U1 (1 MFMA/frag); 4 updates/lane.
// h exchanged via double-buffered LDS tile (stride 40 shorts: 16B-aligned,
// 2-way-max bank aliasing). One lgkm-only barrier per step.
// =============================================================================
__global__ __launch_bounds__(128, 1) void lstm1_fused(
    const float* __restrict__ x,      // [B][T][64] fp32
    const float* __restrict__ W1f, const float* __restrict__ b1f, const float* __restrict__ U1f,
    const float* __restrict__ W1b, const float* __restrict__ b1b, const float* __restrict__ U1b,
    unsigned short* __restrict__ h1)  // [(g*T+t)*16 + sample][64] bf16 bits
{
    __shared__ unsigned short hb[2][16 * 40];
    const int tid  = threadIdx.x;
    const int lane = tid & 63;
    const int wv   = tid >> 6;
    const int n15  = lane & 15, quad = lane >> 4;
    const int d    = blockIdx.x & 1, g = blockIdx.x >> 1;

    const float* W = d ? W1b : W1f;
    const float* U = d ? U1b : U1f;
    const float* bs = d ? b1b : b1f;

    // weight fragments: frag q = 2*i + wv covers gate cols q*16+n15
    bf16x8 Wf[4][2], Uf[4];
    float bias[4];
    #pragma unroll
    for (int i = 0; i < 4; ++i) {
        const int col = (2 * i + wv) * 16 + n15;
        bias[i] = bs[col];
        #pragma unroll
        for (int ks = 0; ks < 2; ++ks) {
            bf16x8 f;
            #pragma unroll
            for (int j = 0; j < 8; ++j)
                f[j] = (short)f2bf(W[(ks * 32 + quad * 8 + j) * G1 + col]);
            Wf[i][ks] = f;
        }
        bf16x8 u;
        #pragma unroll
        for (int j = 0; j < 8; ++j)
            u[j] = (short)f2bf(U[(quad * 8 + j) * G1 + col]);
        Uf[i] = u;
    }

    // zero h(-1) buffer (buf 0)
    #pragma unroll
    for (int i = 0; i < 5; ++i) hb[0][tid + i * 128] = 0;

    f32x4 c = (f32x4)0.0f;
    const float* xl = x + ((size_t)(g * 16 + n15) * T) * 64 + quad * 8;
    unsigned short* h1p = h1 + (size_t)g * T * 16 * 64 + d * 32 + wv * 16 + n15;

    // x prefetch: 4 float4 per step (k = quad*8..+7 and 32+quad*8..+7)
    float4 xqA[4], xqB[4];
    {
        const float* p0 = xl + (size_t)(d ? (T - 1) : 0) * 64;
        xqA[0] = *(const float4*)(p0);      xqA[1] = *(const float4*)(p0 + 4);
        xqA[2] = *(const float4*)(p0 + 32); xqA[3] = *(const float4*)(p0 + 36);
        const float* p1 = xl + (size_t)(d ? (T - 2) : 1) * 64;
        xqB[0] = *(const float4*)(p1);      xqB[1] = *(const float4*)(p1 + 4);
        xqB[2] = *(const float4*)(p1 + 32); xqB[3] = *(const float4*)(p1 + 36);
    }
    lds_barrier();   // hb[0] zeroing visible to both waves

    auto step = [&](int s, float4 (&xq)[4]) {
        const int t = d ? (T - 1 - s) : s;
        const bf16x8 ax0 = pack8(xq[0], xq[1]);
        const bf16x8 ax1 = pack8(xq[2], xq[3]);

        f32x4 a0 = (f32x4)bias[0], a1 = (f32x4)bias[1];
        f32x4 a2 = (f32x4)bias[2], a3 = (f32x4)bias[3];
        a0 = __builtin_amdgcn_mfma_f32_16x16x32_bf16(ax0, Wf[0][0], a0, 0, 0, 0);
        a1 = __builtin_amdgcn_mfma_f32_16x16x32_bf16(ax0, Wf[1][0], a1, 0, 0, 0);
        a2 = __builtin_amdgcn_mfma_f32_16x16x32_bf16(ax0, Wf[2][0], a2, 0, 0, 0);
        a3 = __builtin_amdgcn_mfma_f32_16x16x32_bf16(ax0, Wf[3][0], a3, 0, 0, 0);
        a0 = __builtin_amdgcn_mfma_f32_16x16x32_bf16(ax1, Wf[0][1], a0, 0, 0, 0);
        a1 = __builtin_amdgcn_mfma_f32_16x16x32_bf16(ax1, Wf[1][1], a1, 0, 0, 0);
        a2 = __builtin_amdgcn_mfma_f32_16x16x32_bf16(ax1, Wf[2][1], a2, 0, 0, 0);
        a3 = __builtin_amdgcn_mfma_f32_16x16x32_bf16(ax1, Wf[3][1], a3, 0, 0, 0);

        // prefetch x for s+2
        if (s + 2 < T) {
            const float* pn = xl + (size_t)(d ? (T - 3 - s) : (s + 2)) * 64;
            xq[0] = *(const float4*)(pn);      xq[1] = *(const float4*)(pn + 4);
            xq[2] = *(const float4*)(pn + 32); xq[3] = *(const float4*)(pn + 36);
        }

        // recurrent term: h(s-1) from LDS (A-frag layout)
        const bf16x8 af = *(const bf16x8*)(hb[s & 1] + n15 * 40 + quad * 8);
        a0 = __builtin_amdgcn_mfma_f32_16x16x32_bf16(af, Uf[0], a0, 0, 0, 0);
        a1 = __builtin_amdgcn_mfma_f32_16x16x32_bf16(af, Uf[1], a1, 0, 0, 0);
        a2 = __builtin_amdgcn_mfma_f32_16x16x32_bf16(af, Uf[2], a2, 0, 0, 0);
        a3 = __builtin_amdgcn_mfma_f32_16x16x32_bf16(af, Uf[3], a3, 0, 0, 0);

        // gate updates: lane owns col wv*16+n15, samples quad*4+r
        #pragma unroll
        for (int r = 0; r < 4; ++r) {
            const float ig = sigmoidf_(a0[r]);
            const float fg = sigmoidf_(a1[r]);
            const float gg = tanhf_(a2[r]);
            const float og = sigmoidf_(a3[r]);
            c[r] = fg * c[r] + ig * gg;
            const float h = og * tanhf_(c[r]);
            const unsigned short us = f2bf(h);
            hb[(s + 1) & 1][(quad * 4 + r) * 40 + wv * 16 + n15] = us;
            h1p[((size_t)t * 16 + quad * 4 + r) * 64] = us;
        }
        lds_barrier();
    };

    #pragma unroll 1
    for (int s = 0; s < T; s += 2) {
        step(s, xqA);
        step(s + 1, xqB);
    }
}

// =============================================================================
// K2: layer-2 recurrence with fused h1@W2 (K=64) + U2 (K=16 zero-padded),
// 16 samples per wave, wave = dir; + dense head. Barrier-free recurrence
// (intra-wave LDS roundtrip; DS pipe is in-order per wave).
// =============================================================================
__global__ __launch_bounds__(128, 1) void lstm2_head(
    const unsigned short* __restrict__ h1,
    const float* __restrict__ W2f, const float* __restrict__ b2f, const float* __restrict__ U2f,
    const float* __restrict__ W2b, const float* __restrict__ b2b, const float* __restrict__ U2b,
    const float* __restrict__ W3, const float* __restrict__ b3,
    const float* __restrict__ W4, const float* __restrict__ b4,
    float* __restrict__ out)          // [B][2]
{
    __shared__ unsigned short hb2[2][400];   // stride 24 shorts, zero-padded
    __shared__ float hfin[2][16][16];
    __shared__ float ybuf[16][9];
    const int tid  = threadIdx.x;
    const int lane = tid & 63;
    const int d    = tid >> 6;
    const int n15  = lane & 15, quad = lane >> 4;
    const int g    = blockIdx.x;

    const float* W = d ? W2b : W2f;
    const float* U = d ? U2b : U2f;
    const float* bs = d ? b2b : b2f;

    bf16x8 Wf[4][2], Uf[4];
    float bias[4];
    #pragma unroll
    for (int i = 0; i < 4; ++i) {
        const int col = i * 16 + n15;
        bias[i] = bs[col];
        #pragma unroll
        for (int ks = 0; ks < 2; ++ks) {
            bf16x8 f;
            #pragma unroll
            for (int j = 0; j < 8; ++j)
                f[j] = (short)f2bf(W[(ks * 32 + quad * 8 + j) * G2 + col]);
            Wf[i][ks] = f;
        }
        bf16x8 u;
        #pragma unroll
        for (int j = 0; j < 8; ++j) {
            const int k = quad * 8 + j;
            u[j] = (k < H2) ? (short)f2bf(U[k * G2 + col]) : (short)0;
        }
        Uf[i] = u;
    }

    // zero own dir's h buffer (incl. pad — quad>=2 af reads land in pad)
    #pragma unroll
    for (int i = 0; i < 7; ++i) {
        const int idx = lane + i * 64;
        if (idx < 400) hb2[d][idx] = 0;
    }

    f32x4 c = (f32x4)0.0f;
    float hlast[4] = {0.f, 0.f, 0.f, 0.f};
    const unsigned short* h1l = h1 + (size_t)g * T * 16 * 64 + n15 * 64 + quad * 8;

    bf16x8 hxA0, hxA1, hxB0, hxB1;
    {
        const unsigned short* p0 = h1l + (size_t)(d ? (T - 1) : 0) * 1024;
        hxA0 = *(const bf16x8*)(p0); hxA1 = *(const bf16x8*)(p0 + 32);
        const unsigned short* p1 = h1l + (size_t)(d ? (T - 2) : 1) * 1024;
        hxB0 = *(const bf16x8*)(p1); hxB1 = *(const bf16x8*)(p1 + 32);
    }

    auto step = [&](int s, bf16x8& hx0, bf16x8& hx1) {
        f32x4 a0 = (f32x4)bias[0], a1 = (f32x4)bias[1];
        f32x4 a2 = (f32x4)bias[2], a3 = (f32x4)bias[3];
        a0 = __builtin_amdgcn_mfma_f32_16x16x32_bf16(hx0, Wf[0][0], a0, 0, 0, 0);
        a1 = __builtin_amdgcn_mfma_f32_16x16x32_bf16(hx0, Wf[1][0], a1, 0, 0, 0);
        a2 = __builtin_amdgcn_mfma_f32_16x16x32_bf16(hx0, Wf[2][0], a2, 0, 0, 0);
        a3 = __builtin_amdgcn_mfma_f32_16x16x32_bf16(hx0, Wf[3][0], a3, 0, 0, 0);
        a0 = __builtin_amdgcn_mfma_f32_16x16x32_bf16(hx1, Wf[0][1], a0, 0, 0, 0);
        a1 = __builtin_amdgcn_mfma_f32_16x16x32_bf16(hx1, Wf[1][1], a1, 0, 0, 0);
        a2 = __builtin_amdgcn_mfma_f32_16x16x32_bf16(hx1, Wf[2][1], a2, 0, 0, 0);
        a3 = __builtin_amdgcn_mfma_f32_16x16x32_bf16(hx1, Wf[3][1], a3, 0, 0, 0);

        if (s + 2 < T) {
            const unsigned short* pn = h1l + (size_t)(d ? (T - 3 - s) : (s + 2)) * 1024;
            hx0 = *(const bf16x8*)(pn); hx1 = *(const bf16x8*)(pn + 32);
        }

        const bf16x8 af = *(const bf16x8*)(hb2[d] + n15 * 24 + quad * 8);
        a0 = __builtin_amdgcn_mfma_f32_16x16x32_bf16(af, Uf[0], a0, 0, 0, 0);
        a1 = __builtin_amdgcn_mfma_f32_16x16x32_bf16(af, Uf[1], a1, 0, 0, 0);
        a2 = __builtin_amdgcn_mfma_f32_16x16x32_bf16(af, Uf[2], a2, 0, 0, 0);
        a3 = __builtin_amdgcn_mfma_f32_16x16x32_bf16(af, Uf[3], a3, 0, 0, 0);

        #pragma unroll
        for (int r = 0; r < 4; ++r) {
            const float ig = sigmoidf_(a0[r]);
            const float fg = sigmoidf_(a1[r]);
            const float gg = tanhf_(a2[r]);
            const float og = sigmoidf_(a3[r]);
            c[r] = fg * c[r] + ig * gg;
            hlast[r] = og * tanhf_(c[r]);
            hb2[d][(quad * 4 + r) * 24 + n15] = f2bf(hlast[r]);
        }
    };

    #pragma unroll 1
    for (int s = 0; s < T; s += 2) {
        step(s, hxA0, hxA1);
        step(s + 1, hxB0, hxB1);
    }

    #pragma unroll
    for (int r = 0; r < 4; ++r)
        hfin[d][quad * 4 + r][n15] = hlast[r];
    __syncthreads();

    // head: y = swish([h2f,h2b] @ W3 + b3); out = sigmoid(y @ W4 + b4)
    {
        const int s = tid >> 3, u = tid & 7;      // 16 samples x 8 units
        float a = b3[u];
        #pragma unroll
        for (int k = 0; k < H2; ++k) a += hfin[0][s][k] * W3[k * 8 + u];
        #pragma unroll
        for (int k = 0; k < H2; ++k) a += hfin[1][s][k] * W3[(H2 + k) * 8 + u];
        ybuf[s][u] = a * sigmoidf_(a);
    }
    __syncthreads();
    if (tid < 32) {
        const int s = tid >> 1, o = tid & 1;
        float a = b4[o];
        #pragma unroll
        for (int k = 0; k < 8; ++k) a += ybuf[s][k] * W4[k * 2 + o];
        out[(size_t)(g * 16 + s) * 2 + o] = sigmoidf_(a);
    }
}

extern "C" void kernel_launch(void* const* d_in, const int* in_sizes, int n_in,
                              void* d_out, int out_size, void* d_ws, size_t ws_size,
                              hipStream_t stream) {
    const float* x   = (const float*)d_in[0];
    const float* W1f = (const float*)d_in[1];
    const float* U1f = (const float*)d_in[2];
    const float* b1f = (const float*)d_in[3];
    const float* W1b = (const float*)d_in[4];
    const float* U1b = (const float*)d_in[5];
    const float* b1b = (const float*)d_in[6];
    const float* W2f = (const float*)d_in[7];
    const float* U2f = (const float*)d_in[8];
    const float* b2f = (const float*)d_in[9];
    const float* W2b = (const float*)d_in[10];
    const float* U2b = (const float*)d_in[11];
    const float* b2b = (const float*)d_in[12];
    const float* W3  = (const float*)d_in[13];
    const float* b3  = (const float*)d_in[14];
    const float* W4  = (const float*)d_in[15];
    const float* b4  = (const float*)d_in[16];
    float* out = (float*)d_out;

    const int B = in_sizes[0] / (T * F);
    unsigned short* h1 = (unsigned short*)d_ws;   // B*T*64 bf16 = 64 MB

    lstm1_fused<<<(B / 16) * 2, 128, 0, stream>>>(
        x, W1f, b1f, U1f, W1b, b1b, U1b, h1);
    lstm2_head<<<B / 16, 128, 0, stream>>>(
        h1, W2f, b2f, U2f, W2b, b2b, U2b, W3, b3, W4, b4, out);
}

// Round 6
// 443.054 us; speedup vs baseline: 4.2337x; 1.1926x over previous
//
#include <hip/hip_runtime.h>
#include <hip/hip_bf16.h>

#define T 128
#define F 64
#define H1 32
#define G1 128   // 4*H1
#define H2 16
#define G2 64    // 4*H2

typedef __attribute__((ext_vector_type(8))) short bf16x8;
typedef __attribute__((ext_vector_type(4))) float f32x4;

__device__ __forceinline__ float sigmoidf_(float x) {
    return 1.0f / (1.0f + __expf(-x));
}
__device__ __forceinline__ float tanhf_(float x) {
    return 1.0f - 2.0f / (__expf(2.0f * x) + 1.0f);
}
__device__ __forceinline__ unsigned short f2bf(float f) {
    union { float f; unsigned u; } c; c.f = f;
    unsigned r = c.u + 0x7FFF + ((c.u >> 16) & 1);   // RTNE
    return (unsigned short)(r >> 16);
}
// LDS-only barrier: waits DS ops, does NOT drain vmcnt (global prefetches
// stay in flight across the per-step sync).
__device__ __forceinline__ void lds_barrier() {
    asm volatile("s_waitcnt lgkmcnt(0)" ::: "memory");
    __builtin_amdgcn_s_barrier();
}
// wave-uniform extract of element r from an f32x4 accumulator
__device__ __forceinline__ float ext4(f32x4 v, int r) {
    const float ab = (r & 1) ? v[1] : v[0];
    const float cd = (r & 1) ? v[3] : v[2];
    return (r & 2) ? cd : ab;
}

// =============================================================================
// K0: convert x fp32 -> bf16 in A-fragment-packed layout.
// Per (g = sample-group-of-16, t): 1024 shorts at base (g*T+t)*1024;
// value (sample m, col k): slot = (k>>5)*512 + (m + 16*((k&31)>>3))*8 + (k&7).
// A lane of the LSTM kernel then loads bf16x8 at ks*512 + lane*8 — coalesced.
// =============================================================================
__global__ __launch_bounds__(256) void xcvt(
    const float* __restrict__ x,          // [B][T][64]
    unsigned short* __restrict__ xbf)
{
    const int g  = blockIdx.x;
    const int t0 = blockIdx.y * 4;
    const int m  = threadIdx.x >> 4;      // sample in group
    const int c4 = threadIdx.x & 15;      // float4 index in row
    const int ks   = c4 >> 3;
    const int quad = (c4 & 7) >> 1;
    const int j0   = (c4 & 1) * 4;
    const int slot = ks * 512 + (m + 16 * quad) * 8 + j0;

    #pragma unroll
    for (int tt = 0; tt < 4; ++tt) {
        const int t = t0 + tt;
        const float4 v = *(const float4*)(x + ((size_t)(g * 16 + m) * T + t) * 64 + c4 * 4);
        ushort4 u;
        u.x = f2bf(v.x); u.y = f2bf(v.y); u.z = f2bf(v.z); u.w = f2bf(v.w);
        *(ushort4*)(xbf + (size_t)(g * T + t) * 1024 + slot) = u;
    }
}

// =============================================================================
// K1: layer-1 recurrence with fused x@W1. Block = (g, d), 8 waves:
// wave = (gate-half gh = wv&1, sample-quarter sh = wv>>1). Each wave does its
// gate-half's 12 MFMAs (duplicated across the 4 sh) and the activations for
// C-row quad*4+sh only. h1 written in packed A-frag layout for K2.
// =============================================================================
__global__ __launch_bounds__(512, 4) void lstm1_fused(
    const unsigned short* __restrict__ xbf,
    const float* __restrict__ W1f, const float* __restrict__ b1f, const float* __restrict__ U1f,
    const float* __restrict__ W1b, const float* __restrict__ b1b, const float* __restrict__ U1b,
    unsigned short* __restrict__ h1)     // packed per (g,t), 1024 shorts
{
    __shared__ unsigned short hb[2][16 * 40];
    const int tid  = threadIdx.x;
    const int lane = tid & 63;
    const int wv   = tid >> 6;
    const int gh   = wv & 1;
    const int sh   = wv >> 1;            // 0..3
    const int n15  = lane & 15, quad = lane >> 4;
    const int d    = blockIdx.x & 1, g = blockIdx.x >> 1;

    const float* W  = d ? W1b : W1f;
    const float* U  = d ? U1b : U1f;
    const float* bs = d ? b1b : b1f;

    // frag q = 2*i + gh covers gate cols q*16+n15 (i,f,g,o co-located per col)
    bf16x8 Wf[4][2], Uf[4];
    float bias[4];
    #pragma unroll
    for (int i = 0; i < 4; ++i) {
        const int col = (2 * i + gh) * 16 + n15;
        bias[i] = bs[col];
        #pragma unroll
        for (int ks = 0; ks < 2; ++ks) {
            bf16x8 f;
            #pragma unroll
            for (int j = 0; j < 8; ++j)
                f[j] = (short)f2bf(W[(ks * 32 + quad * 8 + j) * G1 + col]);
            Wf[i][ks] = f;
        }
        bf16x8 u;
        #pragma unroll
        for (int j = 0; j < 8; ++j)
            u[j] = (short)f2bf(U[(quad * 8 + j) * G1 + col]);
        Uf[i] = u;
    }

    // zero h(-1) buffer + pads
    #pragma unroll
    for (int i = 0; i < 3; ++i) {
        const int idx = tid + i * 512;
        if (idx < 1280) ((unsigned short*)hb)[idx] = 0;
    }

    float c = 0.0f;
    const unsigned short* xb = xbf + (size_t)g * T * 1024 + lane * 8;
    // h1 packed store slot for this lane's value (sample=quad*4+sh, col=d*32+gh*16+n15)
    unsigned short* h1b = h1 + (size_t)g * T * 1024
        + d * 512 + (quad * 4 + sh + 16 * (gh * 2 + (n15 >> 3))) * 8 + (n15 & 7);

    bf16x8 xA0, xA1, xB0, xB1;
    {
        const unsigned short* p0 = xb + (size_t)(d ? (T - 1) : 0) * 1024;
        xA0 = *(const bf16x8*)(p0); xA1 = *(const bf16x8*)(p0 + 512);
        const unsigned short* p1 = xb + (size_t)(d ? (T - 2) : 1) * 1024;
        xB0 = *(const bf16x8*)(p1); xB1 = *(const bf16x8*)(p1 + 512);
    }
    lds_barrier();

    auto step = [&](int s, bf16x8& x0, bf16x8& x1) {
        const int t = d ? (T - 1 - s) : s;
        f32x4 a0 = (f32x4)bias[0], a1 = (f32x4)bias[1];
        f32x4 a2 = (f32x4)bias[2], a3 = (f32x4)bias[3];
        a0 = __builtin_amdgcn_mfma_f32_16x16x32_bf16(x0, Wf[0][0], a0, 0, 0, 0);
        a1 = __builtin_amdgcn_mfma_f32_16x16x32_bf16(x0, Wf[1][0], a1, 0, 0, 0);
        a2 = __builtin_amdgcn_mfma_f32_16x16x32_bf16(x0, Wf[2][0], a2, 0, 0, 0);
        a3 = __builtin_amdgcn_mfma_f32_16x16x32_bf16(x0, Wf[3][0], a3, 0, 0, 0);
        a0 = __builtin_amdgcn_mfma_f32_16x16x32_bf16(x1, Wf[0][1], a0, 0, 0, 0);
        a1 = __builtin_amdgcn_mfma_f32_16x16x32_bf16(x1, Wf[1][1], a1, 0, 0, 0);
        a2 = __builtin_amdgcn_mfma_f32_16x16x32_bf16(x1, Wf[2][1], a2, 0, 0, 0);
        a3 = __builtin_amdgcn_mfma_f32_16x16x32_bf16(x1, Wf[3][1], a3, 0, 0, 0);

        if (s + 2 < T) {
            const unsigned short* pn = xb + (size_t)(d ? (T - 3 - s) : (s + 2)) * 1024;
            x0 = *(const bf16x8*)(pn); x1 = *(const bf16x8*)(pn + 512);
        }

        const bf16x8 af = *(const bf16x8*)(hb[s & 1] + n15 * 40 + quad * 8);
        a0 = __builtin_amdgcn_mfma_f32_16x16x32_bf16(af, Uf[0], a0, 0, 0, 0);
        a1 = __builtin_amdgcn_mfma_f32_16x16x32_bf16(af, Uf[1], a1, 0, 0, 0);
        a2 = __builtin_amdgcn_mfma_f32_16x16x32_bf16(af, Uf[2], a2, 0, 0, 0);
        a3 = __builtin_amdgcn_mfma_f32_16x16x32_bf16(af, Uf[3], a3, 0, 0, 0);

        // this wave's single row: quad*4+sh, col gh*16+n15
        const float ig = sigmoidf_(ext4(a0, sh));
        const float fg = sigmoidf_(ext4(a1, sh));
        const float gg = tanhf_(ext4(a2, sh));
        const float og = sigmoidf_(ext4(a3, sh));
        c = fg * c + ig * gg;
        const float h = og * tanhf_(c);
        const unsigned short us = f2bf(h);
        hb[(s + 1) & 1][(quad * 4 + sh) * 40 + gh * 16 + n15] = us;
        h1b[(size_t)t * 1024] = us;
        lds_barrier();
    };

    #pragma unroll 1
    for (int s = 0; s < T; s += 2) {
        step(s, xA0, xA1);
        step(s + 1, xB0, xB1);
    }
}

// =============================================================================
// K2: layer-2 recurrence with fused h1@W2 (K=64) + U2 (K=16 zero-padded) +
// dense head. Block = g, 8 waves: (d = wv&1, sh = wv>>1); MFMAs duplicated
// across sh, each wave activates 1 C-row per lane.
// =============================================================================
__global__ __launch_bounds__(512, 2) void lstm2_head(
    const unsigned short* __restrict__ h1,
    const float* __restrict__ W2f, const float* __restrict__ b2f, const float* __restrict__ U2f,
    const float* __restrict__ W2b, const float* __restrict__ b2b, const float* __restrict__ U2b,
    const float* __restrict__ W3, const float* __restrict__ b3,
    const float* __restrict__ W4, const float* __restrict__ b4,
    float* __restrict__ out)             // [B][2]
{
    __shared__ unsigned short hb2[2][2][400];   // [d][buf], stride 24, padded
    __shared__ float hfin[2][16][16];
    __shared__ float ybuf[16][9];
    const int tid  = threadIdx.x;
    const int lane = tid & 63;
    const int wv   = tid >> 6;
    const int d    = wv & 1;
    const int sh   = wv >> 1;            // 0..3
    const int n15  = lane & 15, quad = lane >> 4;
    const int g    = blockIdx.x;

    const float* W  = d ? W2b : W2f;
    const float* U  = d ? U2b : U2f;
    const float* bs = d ? b2b : b2f;

    bf16x8 Wf[4][2], Uf[4];
    float bias[4];
    #pragma unroll
    for (int i = 0; i < 4; ++i) {
        const int col = i * 16 + n15;
        bias[i] = bs[col];
        #pragma unroll
        for (int ks = 0; ks < 2; ++ks) {
            bf16x8 f;
            #pragma unroll
            for (int j = 0; j < 8; ++j)
                f[j] = (short)f2bf(W[(ks * 32 + quad * 8 + j) * G2 + col]);
            Wf[i][ks] = f;
        }
        bf16x8 u;
        #pragma unroll
        for (int j = 0; j < 8; ++j) {
            const int k = quad * 8 + j;
            u[j] = (k < H2) ? (short)f2bf(U[k * G2 + col]) : (short)0;
        }
        Uf[i] = u;
    }

    #pragma unroll
    for (int i = 0; i < 4; ++i) {
        const int idx = tid + i * 512;
        if (idx < 1600) ((unsigned short*)hb2)[idx] = 0;
    }

    float c = 0.0f, hlast = 0.0f;
    const unsigned short* hl = h1 + (size_t)g * T * 1024 + lane * 8;

    bf16x8 hA0, hA1, hB0, hB1;
    {
        const unsigned short* p0 = hl + (size_t)(d ? (T - 1) : 0) * 1024;
        hA0 = *(const bf16x8*)(p0); hA1 = *(const bf16x8*)(p0 + 512);
        const unsigned short* p1 = hl + (size_t)(d ? (T - 2) : 1) * 1024;
        hB0 = *(const bf16x8*)(p1); hB1 = *(const bf16x8*)(p1 + 512);
    }
    lds_barrier();

    auto step = [&](int s, bf16x8& x0, bf16x8& x1) {
        f32x4 a0 = (f32x4)bias[0], a1 = (f32x4)bias[1];
        f32x4 a2 = (f32x4)bias[2], a3 = (f32x4)bias[3];
        a0 = __builtin_amdgcn_mfma_f32_16x16x32_bf16(x0, Wf[0][0], a0, 0, 0, 0);
        a1 = __builtin_amdgcn_mfma_f32_16x16x32_bf16(x0, Wf[1][0], a1, 0, 0, 0);
        a2 = __builtin_amdgcn_mfma_f32_16x16x32_bf16(x0, Wf[2][0], a2, 0, 0, 0);
        a3 = __builtin_amdgcn_mfma_f32_16x16x32_bf16(x0, Wf[3][0], a3, 0, 0, 0);
        a0 = __builtin_amdgcn_mfma_f32_16x16x32_bf16(x1, Wf[0][1], a0, 0, 0, 0);
        a1 = __builtin_amdgcn_mfma_f32_16x16x32_bf16(x1, Wf[1][1], a1, 0, 0, 0);
        a2 = __builtin_amdgcn_mfma_f32_16x16x32_bf16(x1, Wf[2][1], a2, 0, 0, 0);
        a3 = __builtin_amdgcn_mfma_f32_16x16x32_bf16(x1, Wf[3][1], a3, 0, 0, 0);

        if (s + 2 < T) {
            const unsigned short* pn = hl + (size_t)(d ? (T - 3 - s) : (s + 2)) * 1024;
            x0 = *(const bf16x8*)(pn); x1 = *(const bf16x8*)(pn + 512);
        }

        const bf16x8 af = *(const bf16x8*)(hb2[d][s & 1] + n15 * 24 + quad * 8);
        a0 = __builtin_amdgcn_mfma_f32_16x16x32_bf16(af, Uf[0], a0, 0, 0, 0);
        a1 = __builtin_amdgcn_mfma_f32_16x16x32_bf16(af, Uf[1], a1, 0, 0, 0);
        a2 = __builtin_amdgcn_mfma_f32_16x16x32_bf16(af, Uf[2], a2, 0, 0, 0);
        a3 = __builtin_amdgcn_mfma_f32_16x16x32_bf16(af, Uf[3], a3, 0, 0, 0);

        const float ig = sigmoidf_(ext4(a0, sh));
        const float fg = sigmoidf_(ext4(a1, sh));
        const float gg = tanhf_(ext4(a2, sh));
        const float og = sigmoidf_(ext4(a3, sh));
        c = fg * c + ig * gg;
        hlast = og * tanhf_(c);
        hb2[d][(s + 1) & 1][(quad * 4 + sh) * 24 + n15] = f2bf(hlast);
        lds_barrier();
    };

    #pragma unroll 1
    for (int s = 0; s < T; s += 2) {
        step(s, hA0, hA1);
        step(s + 1, hB0, hB1);
    }

    hfin[d][quad * 4 + sh][n15] = hlast;
    __syncthreads();

    if (tid < 128) {
        const int s = tid >> 3, u = tid & 7;      // 16 samples x 8 units
        float a = b3[u];
        #pragma unroll
        for (int k = 0; k < H2; ++k) a += hfin[0][s][k] * W3[k * 8 + u];
        #pragma unroll
        for (int k = 0; k < H2; ++k) a += hfin[1][s][k] * W3[(H2 + k) * 8 + u];
        ybuf[s][u] = a * sigmoidf_(a);
    }
    __syncthreads();
    if (tid < 32) {
        const int s = tid >> 1, o = tid & 1;
        float a = b4[o];
        #pragma unroll
        for (int k = 0; k < 8; ++k) a += ybuf[s][k] * W4[k * 2 + o];
        out[(size_t)(g * 16 + s) * 2 + o] = sigmoidf_(a);
    }
}

extern "C" void kernel_launch(void* const* d_in, const int* in_sizes, int n_in,
                              void* d_out, int out_size, void* d_ws, size_t ws_size,
                              hipStream_t stream) {
    const float* x   = (const float*)d_in[0];
    const float* W1f = (const float*)d_in[1];
    const float* U1f = (const float*)d_in[2];
    const float* b1f = (const float*)d_in[3];
    const float* W1b = (const float*)d_in[4];
    const float* U1b = (const float*)d_in[5];
    const float* b1b = (const float*)d_in[6];
    const float* W2f = (const float*)d_in[7];
    const float* U2f = (const float*)d_in[8];
    const float* b2f = (const float*)d_in[9];
    const float* W2b = (const float*)d_in[10];
    const float* U2b = (const float*)d_in[11];
    const float* b2b = (const float*)d_in[12];
    const float* W3  = (const float*)d_in[13];
    const float* b3  = (const float*)d_in[14];
    const float* W4  = (const float*)d_in[15];
    const float* b4  = (const float*)d_in[16];
    float* out = (float*)d_out;

    const int B  = in_sizes[0] / (T * F);
    const int NG = B / 16;                       // sample groups

    // ws: xbf (256 KB/group) + h1 (256 KB/group), chunked if ws is small
    const size_t perG = (size_t)T * 1024 * sizeof(unsigned short);  // 256 KB
    int chG = (int)(ws_size / (2 * perG));
    if (chG > NG) chG = NG;
    if (chG < 1) chG = 1;
    unsigned short* xbf = (unsigned short*)d_ws;
    unsigned short* h1  = xbf + (size_t)chG * T * 1024;

    for (int g0 = 0; g0 < NG; g0 += chG) {
        const int cg = (NG - g0 < chG) ? (NG - g0) : chG;
        dim3 gcv(cg, T / 4);
        xcvt<<<gcv, 256, 0, stream>>>(x + (size_t)g0 * 16 * T * F, xbf);
        lstm1_fused<<<cg * 2, 512, 0, stream>>>(
            xbf, W1f, b1f, U1f, W1b, b1b, U1b, h1);
        lstm2_head<<<cg, 512, 0, stream>>>(
            h1, W2f, b2f, U2f, W2b, b2b, U2b, W3, b3, W4, b4,
            out + (size_t)g0 * 16 * 2);
    }
}

// Round 7
// 431.162 us; speedup vs baseline: 4.3504x; 1.0276x over previous
//
#include <hip/hip_runtime.h>
#include <hip/hip_bf16.h>

#define T 128
#define F 64
#define H1 32
#define G1 128   // 4*H1
#define H2 16
#define G2 64    // 4*H2

typedef __attribute__((ext_vector_type(8))) short bf16x8;
typedef __attribute__((ext_vector_type(4))) float f32x4;

__device__ __forceinline__ float sigmoidf_(float x) {
    return 1.0f / (1.0f + __expf(-x));
}
__device__ __forceinline__ float tanhf_(float x) {
    return 1.0f - 2.0f / (__expf(2.0f * x) + 1.0f);
}
__device__ __forceinline__ unsigned short f2bf(float f) {
    union { float f; unsigned u; } c; c.f = f;
    unsigned r = c.u + 0x7FFF + ((c.u >> 16) & 1);   // RTNE
    return (unsigned short)(r >> 16);
}
// LDS-only barrier: waits DS ops, does NOT drain vmcnt (global prefetches
// stay in flight across the per-step sync).
__device__ __forceinline__ void lds_barrier() {
    asm volatile("s_waitcnt lgkmcnt(0)" ::: "memory");
    __builtin_amdgcn_s_barrier();
}

// =============================================================================
// K0: convert x fp32 -> bf16 in A-fragment-packed layout, via LDS transpose.
// Packed layout per (g,t), 1024 shorts: value (sample m, col k) at
//   slot = (k>>5)*512 + (m + 16*((k&31)>>3))*8 + (k&7)
// LSTM lane then loads bf16x8 at ks*512 + lane*8 — one b128, coalesced.
// =============================================================================
__global__ __launch_bounds__(256) void xcvt(
    const float* __restrict__ x,          // [B][T][64]
    unsigned short* __restrict__ xbf)
{
    __shared__ unsigned short tile[1024];
    const int g  = blockIdx.x;
    const int t0 = blockIdx.y * 8;
    const int m  = threadIdx.x >> 4;      // sample in group
    const int c4 = threadIdx.x & 15;      // float4 index in row
    const int ks   = c4 >> 3;
    const int quad = (c4 & 7) >> 1;
    const int j0   = (c4 & 1) * 4;
    const int slot = ks * 512 + (m + 16 * quad) * 8 + j0;

    for (int tt = 0; tt < 8; ++tt) {
        const int t = t0 + tt;
        const float4 v = *(const float4*)(x + ((size_t)(g * 16 + m) * T + t) * 64 + c4 * 4);
        ushort4 u;
        u.x = f2bf(v.x); u.y = f2bf(v.y); u.z = f2bf(v.z); u.w = f2bf(v.w);
        *(ushort4*)(tile + slot) = u;
        __syncthreads();
        // coalesced: 256 threads x 8 B = one contiguous 2 KB burst
        *(uint2*)(xbf + (size_t)(g * T + t) * 1024 + threadIdx.x * 4) =
            *(const uint2*)(tile + threadIdx.x * 4);
        __syncthreads();
    }
}

// =============================================================================
// K1: layer-1 recurrence with fused x@W1. Block = (g, d), 4 waves:
// wave = (gate-half gh = wv&1, sample-half sh = wv>>1). Each wave does its
// gate-half's 12 MFMAs (duplicated 2x across sh) and activates 2 C-rows
// (samples quad*4 + 2*sh + {0,1}). Bias rides as loop-invariant MFMA C.
// =============================================================================
__global__ __launch_bounds__(256, 2) void lstm1_fused(
    const unsigned short* __restrict__ xbf,
    const float* __restrict__ W1f, const float* __restrict__ b1f, const float* __restrict__ U1f,
    const float* __restrict__ W1b, const float* __restrict__ b1b, const float* __restrict__ U1b,
    unsigned short* __restrict__ h1)     // packed per (g,t), 1024 shorts
{
    __shared__ unsigned short hb[2][16 * 40];
    const int tid  = threadIdx.x;
    const int lane = tid & 63;
    const int wv   = __builtin_amdgcn_readfirstlane(tid >> 6);
    const int gh   = wv & 1;
    const int sh   = wv >> 1;            // 0..1
    const int n15  = lane & 15, quad = lane >> 4;
    const int d    = blockIdx.x & 1, g = blockIdx.x >> 1;

    const float* W  = d ? W1b : W1f;
    const float* U  = d ? U1b : U1f;
    const float* bs = d ? b1b : b1f;

    // frag q = 2*i + gh covers gate cols q*16+n15 (i,f,g,o co-located per col)
    bf16x8 Wf[4][2], Uf[4];
    f32x4 biasC[4];
    #pragma unroll
    for (int i = 0; i < 4; ++i) {
        const int col = (2 * i + gh) * 16 + n15;
        biasC[i] = (f32x4)(bs[col]);
        #pragma unroll
        for (int ks = 0; ks < 2; ++ks) {
            bf16x8 f;
            #pragma unroll
            for (int j = 0; j < 8; ++j)
                f[j] = (short)f2bf(W[(ks * 32 + quad * 8 + j) * G1 + col]);
            Wf[i][ks] = f;
        }
        bf16x8 u;
        #pragma unroll
        for (int j = 0; j < 8; ++j)
            u[j] = (short)f2bf(U[(quad * 8 + j) * G1 + col]);
        Uf[i] = u;
    }

    // zero h(-1) buffer + pads (1280 shorts total)
    #pragma unroll
    for (int i = 0; i < 5; ++i) ((unsigned short*)hb)[tid + i * 256] = 0;

    float c0 = 0.0f, c1 = 0.0f;
    const unsigned short* xb = xbf + (size_t)g * T * 1024 + lane * 8;
    // packed h1 slots for this lane's two samples (m = quad*4+2*sh+{0,1})
    unsigned short* h1b0 = h1 + (size_t)g * T * 1024
        + d * 512 + ((quad * 4 + 2 * sh) + 16 * (gh * 2 + (n15 >> 3))) * 8 + (n15 & 7);
    unsigned short* h1b1 = h1b0 + 8;

    bf16x8 xA0, xA1, xB0, xB1;
    {
        const unsigned short* p0 = xb + (size_t)(d ? (T - 1) : 0) * 1024;
        xA0 = *(const bf16x8*)(p0); xA1 = *(const bf16x8*)(p0 + 512);
        const unsigned short* p1 = xb + (size_t)(d ? (T - 2) : 1) * 1024;
        xB0 = *(const bf16x8*)(p1); xB1 = *(const bf16x8*)(p1 + 512);
    }
    lds_barrier();

    auto step = [&](int s, bf16x8& x0, bf16x8& x1) {
        const int t = d ? (T - 1 - s) : s;
        f32x4 a0 = __builtin_amdgcn_mfma_f32_16x16x32_bf16(x0, Wf[0][0], biasC[0], 0, 0, 0);
        f32x4 a1 = __builtin_amdgcn_mfma_f32_16x16x32_bf16(x0, Wf[1][0], biasC[1], 0, 0, 0);
        f32x4 a2 = __builtin_amdgcn_mfma_f32_16x16x32_bf16(x0, Wf[2][0], biasC[2], 0, 0, 0);
        f32x4 a3 = __builtin_amdgcn_mfma_f32_16x16x32_bf16(x0, Wf[3][0], biasC[3], 0, 0, 0);
        a0 = __builtin_amdgcn_mfma_f32_16x16x32_bf16(x1, Wf[0][1], a0, 0, 0, 0);
        a1 = __builtin_amdgcn_mfma_f32_16x16x32_bf16(x1, Wf[1][1], a1, 0, 0, 0);
        a2 = __builtin_amdgcn_mfma_f32_16x16x32_bf16(x1, Wf[2][1], a2, 0, 0, 0);
        a3 = __builtin_amdgcn_mfma_f32_16x16x32_bf16(x1, Wf[3][1], a3, 0, 0, 0);

        if (s + 2 < T) {
            const unsigned short* pn = xb + (size_t)(d ? (T - 3 - s) : (s + 2)) * 1024;
            x0 = *(const bf16x8*)(pn); x1 = *(const bf16x8*)(pn + 512);
        }

        const bf16x8 af = *(const bf16x8*)(hb[s & 1] + n15 * 40 + quad * 8);
        a0 = __builtin_amdgcn_mfma_f32_16x16x32_bf16(af, Uf[0], a0, 0, 0, 0);
        a1 = __builtin_amdgcn_mfma_f32_16x16x32_bf16(af, Uf[1], a1, 0, 0, 0);
        a2 = __builtin_amdgcn_mfma_f32_16x16x32_bf16(af, Uf[2], a2, 0, 0, 0);
        a3 = __builtin_amdgcn_mfma_f32_16x16x32_bf16(af, Uf[3], a3, 0, 0, 0);

        // rows 2*sh and 2*sh+1 of each acc (1 cndmask per extract)
        {   // update 0: sample quad*4 + 2*sh
            const float ig = sigmoidf_(sh ? a0[2] : a0[0]);
            const float fg = sigmoidf_(sh ? a1[2] : a1[0]);
            const float gg = tanhf_(sh ? a2[2] : a2[0]);
            const float og = sigmoidf_(sh ? a3[2] : a3[0]);
            c0 = fg * c0 + ig * gg;
            const float h = og * tanhf_(c0);
            const unsigned short us = f2bf(h);
            hb[(s + 1) & 1][(quad * 4 + 2 * sh) * 40 + gh * 16 + n15] = us;
            h1b0[(size_t)t * 1024] = us;
        }
        {   // update 1: sample quad*4 + 2*sh + 1
            const float ig = sigmoidf_(sh ? a0[3] : a0[1]);
            const float fg = sigmoidf_(sh ? a1[3] : a1[1]);
            const float gg = tanhf_(sh ? a2[3] : a2[1]);
            const float og = sigmoidf_(sh ? a3[3] : a3[1]);
            c1 = fg * c1 + ig * gg;
            const float h = og * tanhf_(c1);
            const unsigned short us = f2bf(h);
            hb[(s + 1) & 1][(quad * 4 + 2 * sh + 1) * 40 + gh * 16 + n15] = us;
            h1b1[(size_t)t * 1024] = us;
        }
        lds_barrier();
    };

    #pragma unroll 1
    for (int s = 0; s < T; s += 2) {
        step(s, xA0, xA1);
        step(s + 1, xB0, xB1);
    }
}

// =============================================================================
// K2: layer-2 recurrence with fused h1@W2 (K=64) + U2 (K=16 zero-padded) +
// dense head. Block = g, 8 waves: (d = wv&1, sh = wv>>1); MFMAs duplicated
// across sh, each wave activates 1 C-row per lane. Bias as invariant C.
// =============================================================================
__global__ __launch_bounds__(512, 2) void lstm2_head(
    const unsigned short* __restrict__ h1,
    const float* __restrict__ W2f, const float* __restrict__ b2f, const float* __restrict__ U2f,
    const float* __restrict__ W2b, const float* __restrict__ b2b, const float* __restrict__ U2b,
    const float* __restrict__ W3, const float* __restrict__ b3,
    const float* __restrict__ W4, const float* __restrict__ b4,
    float* __restrict__ out)             // [B][2]
{
    __shared__ unsigned short hb2[2][2][400];   // [d][buf], stride 24, padded
    __shared__ float hfin[2][16][16];
    __shared__ float ybuf[16][9];
    const int tid  = threadIdx.x;
    const int lane = tid & 63;
    const int wv   = __builtin_amdgcn_readfirstlane(tid >> 6);
    const int d    = wv & 1;
    const int sh   = wv >> 1;            // 0..3
    const int n15  = lane & 15, quad = lane >> 4;
    const int g    = blockIdx.x;

    const float* W  = d ? W2b : W2f;
    const float* U  = d ? U2b : U2f;
    const float* bs = d ? b2b : b2f;

    bf16x8 Wf[4][2], Uf[4];
    f32x4 biasC[4];
    #pragma unroll
    for (int i = 0; i < 4; ++i) {
        const int col = i * 16 + n15;
        biasC[i] = (f32x4)(bs[col]);
        #pragma unroll
        for (int ks = 0; ks < 2; ++ks) {
            bf16x8 f;
            #pragma unroll
            for (int j = 0; j < 8; ++j)
                f[j] = (short)f2bf(W[(ks * 32 + quad * 8 + j) * G2 + col]);
            Wf[i][ks] = f;
        }
        bf16x8 u;
        #pragma unroll
        for (int j = 0; j < 8; ++j) {
            const int k = quad * 8 + j;
            u[j] = (k < H2) ? (short)f2bf(U[k * G2 + col]) : (short)0;
        }
        Uf[i] = u;
    }

    #pragma unroll
    for (int i = 0; i < 4; ++i) {
        const int idx = tid + i * 512;
        if (idx < 1600) ((unsigned short*)hb2)[idx] = 0;
    }

    float c = 0.0f, hlast = 0.0f;
    const unsigned short* hl = h1 + (size_t)g * T * 1024 + lane * 8;

    bf16x8 hA0, hA1, hB0, hB1;
    {
        const unsigned short* p0 = hl + (size_t)(d ? (T - 1) : 0) * 1024;
        hA0 = *(const bf16x8*)(p0); hA1 = *(const bf16x8*)(p0 + 512);
        const unsigned short* p1 = hl + (size_t)(d ? (T - 2) : 1) * 1024;
        hB0 = *(const bf16x8*)(p1); hB1 = *(const bf16x8*)(p1 + 512);
    }
    lds_barrier();

    auto step = [&](int s, bf16x8& x0, bf16x8& x1) {
        f32x4 a0 = __builtin_amdgcn_mfma_f32_16x16x32_bf16(x0, Wf[0][0], biasC[0], 0, 0, 0);
        f32x4 a1 = __builtin_amdgcn_mfma_f32_16x16x32_bf16(x0, Wf[1][0], biasC[1], 0, 0, 0);
        f32x4 a2 = __builtin_amdgcn_mfma_f32_16x16x32_bf16(x0, Wf[2][0], biasC[2], 0, 0, 0);
        f32x4 a3 = __builtin_amdgcn_mfma_f32_16x16x32_bf16(x0, Wf[3][0], biasC[3], 0, 0, 0);
        a0 = __builtin_amdgcn_mfma_f32_16x16x32_bf16(x1, Wf[0][1], a0, 0, 0, 0);
        a1 = __builtin_amdgcn_mfma_f32_16x16x32_bf16(x1, Wf[1][1], a1, 0, 0, 0);
        a2 = __builtin_amdgcn_mfma_f32_16x16x32_bf16(x1, Wf[2][1], a2, 0, 0, 0);
        a3 = __builtin_amdgcn_mfma_f32_16x16x32_bf16(x1, Wf[3][1], a3, 0, 0, 0);

        if (s + 2 < T) {
            const unsigned short* pn = hl + (size_t)(d ? (T - 3 - s) : (s + 2)) * 1024;
            x0 = *(const bf16x8*)(pn); x1 = *(const bf16x8*)(pn + 512);
        }

        const bf16x8 af = *(const bf16x8*)(hb2[d][s & 1] + n15 * 24 + quad * 8);
        a0 = __builtin_amdgcn_mfma_f32_16x16x32_bf16(af, Uf[0], a0, 0, 0, 0);
        a1 = __builtin_amdgcn_mfma_f32_16x16x32_bf16(af, Uf[1], a1, 0, 0, 0);
        a2 = __builtin_amdgcn_mfma_f32_16x16x32_bf16(af, Uf[2], a2, 0, 0, 0);
        a3 = __builtin_amdgcn_mfma_f32_16x16x32_bf16(af, Uf[3], a3, 0, 0, 0);

        const float z0 = (sh & 1) ? ((sh & 2) ? a0[3] : a0[1]) : ((sh & 2) ? a0[2] : a0[0]);
        const float z1 = (sh & 1) ? ((sh & 2) ? a1[3] : a1[1]) : ((sh & 2) ? a1[2] : a1[0]);
        const float z2 = (sh & 1) ? ((sh & 2) ? a2[3] : a2[1]) : ((sh & 2) ? a2[2] : a2[0]);
        const float z3 = (sh & 1) ? ((sh & 2) ? a3[3] : a3[1]) : ((sh & 2) ? a3[2] : a3[0]);
        const float ig = sigmoidf_(z0);
        const float fg = sigmoidf_(z1);
        const float gg = tanhf_(z2);
        const float og = sigmoidf_(z3);
        c = fg * c + ig * gg;
        hlast = og * tanhf_(c);
        hb2[d][(s + 1) & 1][(quad * 4 + sh) * 24 + n15] = f2bf(hlast);
        lds_barrier();
    };

    #pragma unroll 1
    for (int s = 0; s < T; s += 2) {
        step(s, hA0, hA1);
        step(s + 1, hB0, hB1);
    }

    hfin[d][quad * 4 + sh][n15] = hlast;
    __syncthreads();

    if (tid < 128) {
        const int s = tid >> 3, u = tid & 7;      // 16 samples x 8 units
        float a = b3[u];
        #pragma unroll
        for (int k = 0; k < H2; ++k) a += hfin[0][s][k] * W3[k * 8 + u];
        #pragma unroll
        for (int k = 0; k < H2; ++k) a += hfin[1][s][k] * W3[(H2 + k) * 8 + u];
        ybuf[s][u] = a * sigmoidf_(a);
    }
    __syncthreads();
    if (tid < 32) {
        const int s = tid >> 1, o = tid & 1;
        float a = b4[o];
        #pragma unroll
        for (int k = 0; k < 8; ++k) a += ybuf[s][k] * W4[k * 2 + o];
        out[(size_t)(g * 16 + s) * 2 + o] = sigmoidf_(a);
    }
}

extern "C" void kernel_launch(void* const* d_in, const int* in_sizes, int n_in,
                              void* d_out, int out_size, void* d_ws, size_t ws_size,
                              hipStream_t stream) {
    const float* x   = (const float*)d_in[0];
    const float* W1f = (const float*)d_in[1];
    const float* U1f = (const float*)d_in[2];
    const float* b1f = (const float*)d_in[3];
    const float* W1b = (const float*)d_in[4];
    const float* U1b = (const float*)d_in[5];
    const float* b1b = (const float*)d_in[6];
    const float* W2f = (const float*)d_in[7];
    const float* U2f = (const float*)d_in[8];
    const float* b2f = (const float*)d_in[9];
    const float* W2b = (const float*)d_in[10];
    const float* U2b = (const float*)d_in[11];
    const float* b2b = (const float*)d_in[12];
    const float* W3  = (const float*)d_in[13];
    const float* b3  = (const float*)d_in[14];
    const float* W4  = (const float*)d_in[15];
    const float* b4  = (const float*)d_in[16];
    float* out = (float*)d_out;

    const int B  = in_sizes[0] / (T * F);
    const int NG = B / 16;                       // sample groups

    // ws: xbf (256 KB/group) + h1 (256 KB/group), chunked if ws is small
    const size_t perG = (size_t)T * 1024 * sizeof(unsigned short);  // 256 KB
    int chG = (int)(ws_size / (2 * perG));
    if (chG > NG) chG = NG;
    if (chG < 1) chG = 1;
    unsigned short* xbf = (unsigned short*)d_ws;
    unsigned short* h1  = xbf + (size_t)chG * T * 1024;

    for (int g0 = 0; g0 < NG; g0 += chG) {
        const int cg = (NG - g0 < chG) ? (NG - g0) : chG;
        dim3 gcv(cg, T / 8);
        xcvt<<<gcv, 256, 0, stream>>>(x + (size_t)g0 * 16 * T * F, xbf);
        lstm1_fused<<<cg * 2, 256, 0, stream>>>(
            xbf, W1f, b1f, U1f, W1b, b1b, U1b, h1);
        lstm2_head<<<cg, 512, 0, stream>>>(
            h1, W2f, b2f, U2f, W2b, b2b, U2b, W3, b3, W4, b4,
            out + (size_t)g0 * 16 * 2);
    }
}